// Round 1
// baseline (577.623 us; speedup 1.0000x reference)
//
#include <hip/hip_runtime.h>
#include <math.h>

#define DEV __device__ __forceinline__

DEV float sigmoidf_(float x){ return 1.f/(1.f+__expf(-x)); }
DEV float siluf_(float x){ return x/(1.f+__expf(-x)); }
DEV float softplusf_(float x){ return (x>20.f)? x : log1pf(__expf(x)); }

// row index remap: mode 0 identity; mode 1 mamba interleave/deinterleave;
// mode 2 shifted-window gather/scatter (roll -4,-4 then 8x8 windows)
DEV int map_row(int r, int mode){
  if(mode==1){
    int b=r/4608; int gl=r-b*4608;
    return ((gl&1)*2+b)*2304 + (gl>>1);
  }
  if(mode==2){
    int widx=r>>6, n=r&63;
    int b=widx/36, t=widx-b*36;
    int wi=t/6, wj=t-wi*6;
    int h2=wi*8+(n>>3), w2=wj*8+(n&7);
    int ho=h2+4; if(ho>=48) ho-=48;
    int wo=w2+4; if(wo>=48) wo-=48;
    return b*2304 + ho*48 + wo;
  }
  return r;
}

// ---------------- LayerNorm over C=192, 4 rows (waves) per block ----------------
__global__ __launch_bounds__(256) void k_ln(const float* __restrict__ in, const float* __restrict__ w,
                                            const float* __restrict__ b, float* __restrict__ out){
  int warp=threadIdx.x>>6, lane=threadIdx.x&63;
  int row=blockIdx.x*4+warp;
  const float* ip=in+(size_t)row*192;
  float v0=ip[lane], v1=ip[lane+64], v2=ip[lane+128];
  float s=v0+v1+v2, sq=v0*v0+v1*v1+v2*v2;
  #pragma unroll
  for(int off=32;off;off>>=1){ s+=__shfl_xor(s,off); sq+=__shfl_xor(sq,off); }
  float mean=s*(1.f/192.f), var=sq*(1.f/192.f)-mean*mean;
  float inv=rsqrtf(var+1e-5f);
  float* op=out+(size_t)row*192;
  op[lane]    =(v0-mean)*inv*w[lane]    +b[lane];
  op[lane+64] =(v1-mean)*inv*w[lane+64] +b[lane+64];
  op[lane+128]=(v2-mean)*inv*w[lane+128]+b[lane+128];
}

// ---------------- generic fp32 GEMM: Out[map_s(m)][col_off+n] = A[map_g(m)]·W[n] (+bias/gelu/res)
// tile 64x64, BK=16, 256 threads, 4x4 per thread. epi: 0 none/bias, 2 bias+gelu, 3 bias+res
__global__ __launch_bounds__(256) void k_gemm(const float* __restrict__ A, const float* __restrict__ W,
    const float* __restrict__ bias, const float* __restrict__ res, float* __restrict__ O,
    int N, int K, int lda, int ldo, int col_off, int gmode, int smode, int epi){
  __shared__ float sA[16][68];
  __shared__ float sB[16][68];
  int tid=threadIdx.x;
  int bm=blockIdx.y*64, bn=blockIdx.x*64;
  int lr=tid>>2, lk=(tid&3)*4;
  int ty=tid>>4, tx=tid&15;
  int arow=map_row(bm+lr,gmode);
  const float* Ap=A+(size_t)arow*lda+lk;
  int brow=bn+lr;
  bool bok=brow<N;
  const float* Wp=W+(size_t)(bok?brow:0)*K+lk;
  float acc[4][4]={};
  for(int k0=0;k0<K;k0+=16){
    float a0=Ap[0],a1=Ap[1],a2=Ap[2],a3=Ap[3];
    float b0=0,b1=0,b2=0,b3=0;
    if(bok){ b0=Wp[0];b1=Wp[1];b2=Wp[2];b3=Wp[3]; }
    sA[lk][lr]=a0; sA[lk+1][lr]=a1; sA[lk+2][lr]=a2; sA[lk+3][lr]=a3;
    sB[lk][lr]=b0; sB[lk+1][lr]=b1; sB[lk+2][lr]=b2; sB[lk+3][lr]=b3;
    __syncthreads();
    #pragma unroll
    for(int kk=0;kk<16;kk++){
      float av[4],bv[4];
      #pragma unroll
      for(int u=0;u<4;u++) av[u]=sA[kk][ty*4+u];
      #pragma unroll
      for(int v=0;v<4;v++) bv[v]=sB[kk][tx*4+v];
      #pragma unroll
      for(int u=0;u<4;u++)
        #pragma unroll
        for(int v=0;v<4;v++) acc[u][v]+=av[u]*bv[v];
    }
    __syncthreads();
    Ap+=16; Wp+=16;
  }
  #pragma unroll
  for(int u=0;u<4;u++){
    int m=bm+ty*4+u;
    int orow=map_row(m,smode);
    float* op=O+(size_t)orow*ldo+col_off;
    const float* rp=res? res+(size_t)orow*ldo : nullptr;
    #pragma unroll
    for(int v=0;v<4;v++){
      int nn=bn+tx*4+v;
      if(nn<N){
        float val=acc[u][v];
        if(bias) val+=bias[nn];
        if(epi==2) val=0.5f*val*(1.f+erff(val*0.70710678118654752f));
        else if(epi==3) val+=rp[nn];
        op[nn]=val;
      }
    }
  }
}

// ---------------- causal depthwise conv4 + bias + silu over zx cols [384,896) ----------------
__global__ __launch_bounds__(256) void k_conv(const float* __restrict__ zx, const float* __restrict__ cw,
                       const float* __restrict__ cb, float* __restrict__ xbc){
  int e=blockIdx.x*256+threadIdx.x;
  if(e>=2*4608*512) return;
  int ch=e&511; int rl=e>>9;      // rl = b*4608+l
  int l=rl%4608;
  float acc=cb[ch];
  const float* base=zx+(size_t)rl*902+384+ch;
  float w0=cw[ch*4],w1=cw[ch*4+1],w2=cw[ch*4+2],w3=cw[ch*4+3];
  if(l>=3) acc+=base[-3*902]*w0;
  if(l>=2) acc+=base[-2*902]*w1;
  if(l>=1) acc+=base[-902]*w2;
  acc+=base[0]*w3;
  xbc[e]=siluf_(acc);
}

// ---------------- dt softplus, a = dt*(-exp(A_log)), per-chunk inclusive cumsum ----------------
__global__ __launch_bounds__(128) void k_prep(const float* __restrict__ zx, const float* __restrict__ dt_bias,
    const float* __restrict__ A_log, float* __restrict__ dtb, float* __restrict__ acs, float* __restrict__ csum){
  int bid=blockIdx.x;
  int c=bid%36, h=(bid/36)%6, b=bid/216;
  int l=threadIdx.x;
  int row=b*4608+c*128+l;
  float xv=zx[(size_t)row*902+896+h]+dt_bias[h];
  float dt=softplusf_(xv);
  float a=-__expf(A_log[h])*dt;
  dtb[row*6+h]=dt;
  __shared__ float sb[128];
  sb[l]=a; __syncthreads();
  for(int off=1;off<128;off<<=1){
    float add=(l>=off)? sb[l-off]:0.f;
    __syncthreads();
    sb[l]+=add;
    __syncthreads();
  }
  acs[((size_t)(b*6+h)*36+c)*128+l]=sb[l];
  if(l==127) csum[(b*6+h)*36+c]=sb[127];
}

// ---------------- per-chunk states: st[p][n] = sum_l B[l][n]*exp(tot-acs[l])*X[l][p] ----------------
__global__ __launch_bounds__(256) void k_states(const float* __restrict__ xbc, const float* __restrict__ dtb,
    const float* __restrict__ acs, const float* __restrict__ csum, float* __restrict__ st){
  int bid=blockIdx.x;
  int h=bid%6, c=(bid/6)%36, b=bid/216;
  __shared__ float sB[128][64];
  __shared__ float sX[128][64];
  int tid=threadIdx.x;
  int base_row=b*4608+c*128;
  const float* acsp=acs+((size_t)(b*6+h)*36+c)*128;
  float tot=csum[(b*6+h)*36+c];
  for(int i=tid;i<8192;i+=256){
    int l=i>>6, n=i&63;
    int row=base_row+l;
    sB[l][n]=xbc[(size_t)row*512+384+n];
    sX[l][n]=xbc[(size_t)row*512+h*64+n]*dtb[row*6+h]*__expf(tot-acsp[l]);
  }
  __syncthreads();
  float* op=st+((size_t)((b*36+c)*6+h))*4096;
  for(int i=tid;i<4096;i+=256){
    int p=i>>6, n=i&63;
    float acc=0;
    #pragma unroll 4
    for(int l=0;l<128;l++) acc+=sX[l][p]*sB[l][n];
    op[i]=acc;
  }
}

// ---------------- sequential chunk scan: prev[c] = carry; carry = carry*exp(s_c) + states[c] ----------------
__global__ __launch_bounds__(256) void k_scan(const float* __restrict__ st, const float* __restrict__ csum,
                                              float* __restrict__ prevb){
  int bid=blockIdx.x;
  int seg=bid&15, bh=bid>>4;
  int b=bh/6, h=bh%6;
  int e=seg*256+threadIdx.x;
  float carry=0.f;
  for(int c=0;c<36;c++){
    size_t idx=((size_t)((b*36+c)*6+h))*4096+e;
    prevb[idx]=carry;
    carry=carry*__expf(csum[(b*6+h)*36+c])+st[idx];
  }
}

// ---------------- M[l][s] = (l>=s) exp(acs[l]-acs[s]) * (C_l · B_s) ----------------
__global__ __launch_bounds__(256) void k_scores(const float* __restrict__ xbc, const float* __restrict__ acs,
                                                float* __restrict__ Mb){
  int bid=blockIdx.x;
  int h=bid%6, c=(bid/6)%36, b=bid/216;
  __shared__ float sC[128][64];
  __shared__ float sBt[64][65];
  int tid=threadIdx.x;
  int base_row=b*4608+c*128;
  const float* acsp=acs+((size_t)(b*6+h)*36+c)*128;
  for(int i=tid;i<8192;i+=256){ int l=i>>6,n=i&63; sC[l][n]=xbc[(size_t)(base_row+l)*512+448+n]; }
  float* Mp=Mb+((size_t)((b*36+c)*6+h))*16384;
  for(int half=0;half<2;half++){
    __syncthreads();
    for(int i=tid;i<4096;i+=256){ int s=i>>6,n=i&63; sBt[s][n]=xbc[(size_t)(base_row+half*64+s)*512+384+n]; }
    __syncthreads();
    for(int i=tid;i<8192;i+=256){
      int l=i>>6, sl=i&63, s=half*64+sl;
      float v=0.f;
      if(l>=s){
        float d=0;
        #pragma unroll 8
        for(int n=0;n<64;n++) d+=sC[l][n]*sBt[sl][n];
        v=__expf(acsp[l]-acsp[s])*d;
      }
      Mp[l*128+s]=v;
    }
  }
}

// ---------------- Y = M @ X (chunk-local) ----------------
__global__ __launch_bounds__(256) void k_y1(const float* __restrict__ Mb, const float* __restrict__ xbc,
    const float* __restrict__ dtb, float* __restrict__ Y){
  int bid=blockIdx.x;
  int h=bid%6, c=(bid/6)%36, b=bid/216;
  __shared__ float sX[128][64];
  __shared__ float sM[128][33];
  int tid=threadIdx.x;
  int base_row=b*4608+c*128;
  for(int i=tid;i<8192;i+=256){
    int l=i>>6,p=i&63; int row=base_row+l;
    sX[l][p]=xbc[(size_t)row*512+h*64+p]*dtb[row*6+h];
  }
  const float* Mp=Mb+((size_t)((b*36+c)*6+h))*16384;
  float acc[32];
  #pragma unroll
  for(int j=0;j<32;j++) acc[j]=0.f;
  int p=tid&63, l0=tid>>6;
  for(int stile=0;stile<4;stile++){
    __syncthreads();
    for(int i=tid;i<4096;i+=256){ int l=i>>5,s=i&31; sM[l][s]=Mp[l*128+stile*32+s]; }
    __syncthreads();
    #pragma unroll
    for(int j=0;j<32;j++){
      int l=l0+4*j;
      float a=acc[j];
      #pragma unroll 8
      for(int s=0;s<32;s++) a+=sM[l][s]*sX[stile*32+s][p];
      acc[j]=a;
    }
  }
  #pragma unroll
  for(int j=0;j<32;j++){
    int l=l0+4*j; int row=base_row+l;
    Y[(size_t)row*384+h*64+p]=acc[j];
  }
}

// ---------------- Y += exp(acs[l]) * (C_l · prev[p]) + xp*D[h] ----------------
__global__ __launch_bounds__(256) void k_y2(const float* __restrict__ xbc, const float* __restrict__ prevb,
    const float* __restrict__ acs, const float* __restrict__ Dv, float* __restrict__ Y){
  int bid=blockIdx.x;
  int h=bid%6, c=(bid/6)%36, b=bid/216;
  __shared__ float sC[128][64];
  __shared__ float sP[64][65];
  int tid=threadIdx.x;
  int base_row=b*4608+c*128;
  const float* acsp=acs+((size_t)(b*6+h)*36+c)*128;
  for(int i=tid;i<8192;i+=256){ int l=i>>6,n=i&63; sC[l][n]=xbc[(size_t)(base_row+l)*512+448+n]; }
  const float* pp=prevb+((size_t)((b*36+c)*6+h))*4096;
  for(int i=tid;i<4096;i+=256){ int p_=i>>6,n=i&63; sP[p_][n]=pp[i]; }
  __syncthreads();
  float Dh=Dv[h];
  int p=tid&63, l0=tid>>6;
  #pragma unroll
  for(int j=0;j<32;j++){
    int l=l0+4*j;
    float off=0;
    #pragma unroll 8
    for(int n=0;n<64;n++) off+=sC[l][n]*sP[p][n];
    int row=base_row+l;
    size_t yi=(size_t)row*384+h*64+p;
    float xpv=xbc[(size_t)row*512+h*64+p];
    Y[yi]+=off*__expf(acsp[l])+xpv*Dh;
  }
}

// ---------------- y = Y * silu(z), RMSNorm * norm_w ----------------
__global__ __launch_bounds__(256) void k_rmsgate(const float* __restrict__ Y, const float* __restrict__ zx,
    const float* __restrict__ nw, float* __restrict__ yn){
  int warp=threadIdx.x>>6, lane=threadIdx.x&63;
  int row=blockIdx.x*4+warp;
  float v[6]; float ss=0.f;
  #pragma unroll
  for(int j=0;j<6;j++){
    int cidx=lane+64*j;
    float y=Y[(size_t)row*384+cidx];
    float z=zx[(size_t)row*902+cidx];
    y*=siluf_(z);
    v[j]=y; ss+=y*y;
  }
  #pragma unroll
  for(int off=32;off;off>>=1) ss+=__shfl_xor(ss,off);
  float sc=rsqrtf(ss*(1.f/384.f)+1e-5f);
  #pragma unroll
  for(int j=0;j<6;j++){
    int cidx=lane+64*j;
    yn[(size_t)row*384+cidx]=v[j]*sc*nw[cidx];
  }
}

// ---------------- windowed attention core: one (window,head) per 64-thread block ----------------
__global__ __launch_bounds__(64) void k_att2(const float* __restrict__ qkv, const float* __restrict__ xn,
    const float* __restrict__ gw, const float* __restrict__ gb, float* __restrict__ obuf){
  int bid=blockIdx.x;
  int widx=bid/6, head=bid-widx*6;
  int b=widx/36, t=widx-b*36;
  int wi=t/6, wj=t-wi*6;
  int n=threadIdx.x;
  __shared__ float sK[64][32], sV[64][32], sS[64][65];
  size_t qbase=(size_t)(widx*64+n)*576;
  float q[32];
  #pragma unroll
  for(int d=0;d<32;d++){
    q[d]=qkv[qbase+head*32+d];
    sK[n][d]=qkv[qbase+192+head*32+d];
    sV[n][d]=qkv[qbase+384+head*32+d];
  }
  int h2=wi*8+(n>>3), w2=wj*8+(n&7);
  int rh=(h2<40)?0:((h2<44)?1:2);
  int rw=(w2<40)?0:((w2<44)?1:2);
  int myid=rh*3+rw;
  __syncthreads();
  const float scale=0.17677669529663687f;
  for(int j=0;j<64;j++){
    float sc=0;
    #pragma unroll
    for(int d=0;d<32;d++) sc+=q[d]*sK[j][d];
    int hj=wi*8+(j>>3), wjj=wj*8+(j&7);
    int rhj=(hj<40)?0:((hj<44)?1:2);
    int rwj=(wjj<40)?0:((wjj<44)?1:2);
    float m=((rhj*3+rwj)!=myid)? -100.f:0.f;
    sS[n][j]=sc*scale+m;
  }
  float mx=-1e30f;
  for(int j=0;j<64;j++) mx=fmaxf(mx,sS[n][j]);
  float den=0;
  for(int j=0;j<64;j++){ float p=__expf(sS[n][j]-mx); sS[n][j]=p; den+=p; }
  float o[32];
  #pragma unroll
  for(int d=0;d<32;d++) o[d]=0.f;
  for(int j=0;j<64;j++){
    float p=sS[n][j];
    #pragma unroll
    for(int d=0;d<32;d++) o[d]+=p*sV[j][d];
  }
  int xrow=map_row(widx*64+n,2);
  const float* xp=xn+(size_t)xrow*192;
  const float* gwp=gw+head*192;
  float g=0;
  for(int cidx=0;cidx<192;cidx++) g+=xp[cidx]*gwp[cidx];
  g=sigmoidf_(g+gb[head]);
  float fac=g/den;
  float* op=obuf+(size_t)(widx*64+n)*192+head*32;
  #pragma unroll
  for(int d=0;d<32;d++) op[d]=o[d]*fac;
}

// ---------------- ECA pooling (two-stage, deterministic) ----------------
__global__ __launch_bounds__(192) void k_pool1(const float* __restrict__ xf, float* __restrict__ partial){
  int bid=blockIdx.x; int b=bid/18, seg=bid%18;
  int cidx=threadIdx.x;
  const float* p=xf+((size_t)b*2304+seg*128)*192+cidx;
  float s=0;
  for(int l=0;l<128;l++) s+=p[(size_t)l*192];
  partial[bid*192+cidx]=s;
}

__global__ __launch_bounds__(768) void k_ca(const float* __restrict__ partial, const float* __restrict__ ecaw,
                                            float* __restrict__ ca){
  int tid=threadIdx.x;            // 0..767
  int b=tid/192, cidx=tid%192;
  float s=0;
  for(int k=0;k<18;k++) s+=partial[(b*18+k)*192+cidx];
  float pv=s*(1.f/2304.f);
  __shared__ float sP[768];
  sP[tid]=pv; __syncthreads();
  float left =(cidx>0)?   sP[tid-1]:0.f;
  float right=(cidx<191)? sP[tid+1]:0.f;
  ca[tid]=sigmoidf_(ecaw[0]*left+ecaw[1]*pv+ecaw[2]*right);
}

// ---------------- xo = x + xf * ca ----------------
__global__ __launch_bounds__(256) void k_xo(const float* __restrict__ x, const float* __restrict__ xf,
                                            const float* __restrict__ ca, float* __restrict__ xo){
  int e=blockIdx.x*256+threadIdx.x;
  if(e>=4*2304*192) return;
  int cidx=e%192;
  int b=e/(192*2304);
  xo[e]=x[e]+xf[e]*ca[b*192+cidx];
}

extern "C" void kernel_launch(void* const* d_in, const int* in_sizes, int n_in,
                              void* d_out, int out_size, void* d_ws, size_t ws_size,
                              hipStream_t stream){
  const float* x     =(const float*)d_in[0];
  const float* n1w   =(const float*)d_in[3];
  const float* n1b   =(const float*)d_in[4];
  const float* m_in_w=(const float*)d_in[5];
  const float* m_cw  =(const float*)d_in[6];
  const float* m_cb  =(const float*)d_in[7];
  const float* m_dtb =(const float*)d_in[8];
  const float* m_Al  =(const float*)d_in[9];
  const float* m_D   =(const float*)d_in[10];
  const float* m_nw  =(const float*)d_in[11];
  const float* m_ow  =(const float*)d_in[12];
  const float* qkvw  =(const float*)d_in[13];
  const float* qkvb  =(const float*)d_in[14];
  const float* projw =(const float*)d_in[15];
  const float* projb =(const float*)d_in[16];
  const float* gatew =(const float*)d_in[17];
  const float* gateb =(const float*)d_in[18];
  const float* fusw  =(const float*)d_in[19];
  const float* fusb  =(const float*)d_in[20];
  const float* ecaw  =(const float*)d_in[21];
  const float* n2w   =(const float*)d_in[22];
  const float* n2b   =(const float*)d_in[23];
  const float* fc1w  =(const float*)d_in[24];
  const float* fc1b  =(const float*)d_in[25];
  const float* fc2w  =(const float*)d_in[26];
  const float* fc2b  =(const float*)d_in[27];
  float* out=(float*)d_out;
  float* ws=(float*)d_ws;

  // arena (floats); total 29,067,776 floats = 116.3 MB, with lifetime-based aliasing
  float* xn   = ws + 0;          // 1,769,472   live: LN1 .. att2
  float* zx   = ws + 1769472;    // 8,312,832   live: in_proj .. rmsgate
  float* xbc  = ws + 10082304;   // 4,718,592   live: conv .. y2
  float* dtb  = ws + 14800896;   //    55,296   live: prep .. y1
  float* acs  = ws + 14856192;   //    55,296   live: prep .. y2
  float* csum = ws + 14911488;   //       512
  float* st   = ws + 14912000;   // 3,538,944   states: live .. scan
  float* prevb= ws + 18450944;   // 3,538,944   live: scan .. y2
  float* Mb   = ws + 21989888;   // 7,077,888   live: scores .. y1
  // aliases (disjoint lifetimes)
  float* Y    = st;              // y1 .. rmsgate
  float* xcat = zx;              // out_proj .. fusion (9216x384)
  float* obuf = xbc;             // att2 .. proj
  float* yn   = Mb;              // rmsgate .. out_proj (9216x384)
  float* qkv  = Mb;              // qkv gemm .. att2 (9216x576)
  float* h1   = Mb;              // fc1 .. fc2 (9216x768)
  float* xf   = st;              // fusion .. xo
  float* xo   = prevb;           // xo .. fc2
  float* hbuf = xn;              // ln2 .. fc1
  float* partial = dtb;          // pool
  float* ca   = acs;             // ca .. xo

  // 1. LN1
  k_ln<<<2304,256,0,stream>>>(x,n1w,n1b,xn);
  // 2. in_proj (gather: mamba interleave)
  k_gemm<<<dim3(15,144),256,0,stream>>>(xn,m_in_w,nullptr,nullptr,zx, 902,192, 192,902,0, 1,0,0);
  // 3. depthwise conv + silu
  k_conv<<<18432,256,0,stream>>>(zx,m_cw,m_cb,xbc);
  // 4. dt/cumsum prep
  k_prep<<<432,128,0,stream>>>(zx,m_dtb,m_Al,dtb,acs,csum);
  // 5. per-chunk states
  k_states<<<432,256,0,stream>>>(xbc,dtb,acs,csum,st);
  // 6. chunk scan
  k_scan<<<192,256,0,stream>>>(st,csum,prevb);
  // 7. decay-score matrices
  k_scores<<<432,256,0,stream>>>(xbc,acs,Mb);
  // 8. Y = M @ X   (Y overlays dead states)
  k_y1<<<432,256,0,stream>>>(Mb,xbc,dtb,Y);
  // 9. Y += off-diag + D residual
  k_y2<<<432,256,0,stream>>>(xbc,prevb,acs,m_D,Y);
  // 10. gated RMS norm
  k_rmsgate<<<2304,256,0,stream>>>(Y,zx,m_nw,yn);
  // 11. mamba out_proj -> xcat[:, 0:192] (scatter: de-interleave)
  k_gemm<<<dim3(3,144),256,0,stream>>>(yn,m_ow,nullptr,nullptr,xcat, 192,384, 384,384,0, 0,1,0);
  // 12. qkv (gather: shifted windows)
  k_gemm<<<dim3(9,144),256,0,stream>>>(xn,qkvw,qkvb,nullptr,qkv, 576,192, 192,576,0, 2,0,0);
  // 13. attention core + gate
  k_att2<<<864,64,0,stream>>>(qkv,xn,gatew,gateb,obuf);
  // 14. attn proj -> xcat[:, 192:384] (scatter: reverse windows)
  k_gemm<<<dim3(3,144),256,0,stream>>>(obuf,projw,projb,nullptr,xcat, 192,192, 192,384,192, 0,2,0);
  // 15. fusion
  k_gemm<<<dim3(3,144),256,0,stream>>>(xcat,fusw,fusb,nullptr,xf, 192,384, 384,192,0, 0,0,0);
  // 16. ECA
  k_pool1<<<72,192,0,stream>>>(xf,partial);
  k_ca<<<1,768,0,stream>>>(partial,ecaw,ca);
  // 17. xo = x + xf*ca
  k_xo<<<6912,256,0,stream>>>(x,xf,ca,xo);
  // 18. LN2
  k_ln<<<2304,256,0,stream>>>(xo,n2w,n2b,hbuf);
  // 19. fc1 + gelu
  k_gemm<<<dim3(12,144),256,0,stream>>>(hbuf,fc1w,fc1b,nullptr,h1, 768,192, 192,768,0, 0,0,2);
  // 20. fc2 + residual -> out
  k_gemm<<<dim3(3,144),256,0,stream>>>(h1,fc2w,fc2b,xo,out, 192,768, 768,192,0, 0,0,3);
}

// Round 2
// 555.263 us; speedup vs baseline: 1.0403x; 1.0403x over previous
//
#include <hip/hip_runtime.h>
#include <math.h>

#define DEV __device__ __forceinline__

DEV float sigmoidf_(float x){ return 1.f/(1.f+__expf(-x)); }
DEV float siluf_(float x){ return x/(1.f+__expf(-x)); }
DEV float softplusf_(float x){ return (x>20.f)? x : log1pf(__expf(x)); }

// row index remap: mode 0 identity; mode 1 mamba interleave/deinterleave;
// mode 2 shifted-window gather/scatter (roll -4,-4 then 8x8 windows)
DEV int map_row(int r, int mode){
  if(mode==1){
    int b=r/4608; int gl=r-b*4608;
    return ((gl&1)*2+b)*2304 + (gl>>1);
  }
  if(mode==2){
    int widx=r>>6, n=r&63;
    int b=widx/36, t=widx-b*36;
    int wi=t/6, wj=t-wi*6;
    int h2=wi*8+(n>>3), w2=wj*8+(n&7);
    int ho=h2+4; if(ho>=48) ho-=48;
    int wo=w2+4; if(wo>=48) wo-=48;
    return b*2304 + ho*48 + wo;
  }
  return r;
}

// ---------------- LayerNorm over C=192, 4 rows (waves) per block ----------------
__global__ __launch_bounds__(256) void k_ln(const float* __restrict__ in, const float* __restrict__ w,
                                            const float* __restrict__ b, float* __restrict__ out){
  int warp=threadIdx.x>>6, lane=threadIdx.x&63;
  int row=blockIdx.x*4+warp;
  const float* ip=in+(size_t)row*192;
  float v0=ip[lane], v1=ip[lane+64], v2=ip[lane+128];
  float s=v0+v1+v2, sq=v0*v0+v1*v1+v2*v2;
  #pragma unroll
  for(int off=32;off;off>>=1){ s+=__shfl_xor(s,off); sq+=__shfl_xor(sq,off); }
  float mean=s*(1.f/192.f), var=sq*(1.f/192.f)-mean*mean;
  float inv=rsqrtf(var+1e-5f);
  float* op=out+(size_t)row*192;
  op[lane]    =(v0-mean)*inv*w[lane]    +b[lane];
  op[lane+64] =(v1-mean)*inv*w[lane+64] +b[lane+64];
  op[lane+128]=(v2-mean)*inv*w[lane+128]+b[lane+128];
}

// ---------------- fp32 GEMM: 128x64 tile, 256 thr, 8x4/thread ----------------
// Out[map_s(m)][col_off+n] = A[map_g(m)]·W[n]; epi: 0 none/bias, 2 bias+gelu, 3 bias+res
__global__ __launch_bounds__(256) void k_gemm2(const float* __restrict__ A, const float* __restrict__ W,
    const float* __restrict__ bias, const float* __restrict__ res, float* __restrict__ O,
    int N, int K, int lda, int ldo, int col_off, int gmode, int smode, int epi){
  __shared__ float sA[16][132];
  __shared__ float sB[16][68];
  int tid=threadIdx.x;
  int bm=blockIdx.y*128, bn=blockIdx.x*64;
  int alr=tid>>1, akb=(tid&1)*8;
  int arow=map_row(bm+alr,gmode);
  const float* Ap=A+(size_t)arow*lda+akb;
  int blr=tid>>2, bkb=(tid&3)*4;
  int brow=bn+blr;
  bool bok=brow<N;
  const float* Wp=W+(size_t)(bok?brow:0)*K+bkb;
  int ty=tid>>4, tx=tid&15;
  float acc[8][4]={};
  for(int k0=0;k0<K;k0+=16){
    float4 a0=*(const float4*)(Ap);
    float4 a1=*(const float4*)(Ap+4);
    float4 b0=bok? *(const float4*)(Wp) : float4{0.f,0.f,0.f,0.f};
    sA[akb+0][alr]=a0.x; sA[akb+1][alr]=a0.y; sA[akb+2][alr]=a0.z; sA[akb+3][alr]=a0.w;
    sA[akb+4][alr]=a1.x; sA[akb+5][alr]=a1.y; sA[akb+6][alr]=a1.z; sA[akb+7][alr]=a1.w;
    sB[bkb+0][blr]=b0.x; sB[bkb+1][blr]=b0.y; sB[bkb+2][blr]=b0.z; sB[bkb+3][blr]=b0.w;
    __syncthreads();
    #pragma unroll
    for(int kk=0;kk<16;kk++){
      float av[8],bb[4];
      #pragma unroll
      for(int u=0;u<8;u++) av[u]=sA[kk][ty*8+u];
      #pragma unroll
      for(int v=0;v<4;v++) bb[v]=sB[kk][tx*4+v];
      #pragma unroll
      for(int u=0;u<8;u++)
        #pragma unroll
        for(int v=0;v<4;v++) acc[u][v]+=av[u]*bb[v];
    }
    __syncthreads();
    Ap+=16; Wp+=16;
  }
  #pragma unroll
  for(int u=0;u<8;u++){
    int m=bm+ty*8+u;
    int orow=map_row(m,smode);
    float* op=O+(size_t)orow*ldo+col_off;
    const float* rp=res? res+(size_t)orow*ldo : nullptr;
    #pragma unroll
    for(int v=0;v<4;v++){
      int nn=bn+tx*4+v;
      if(nn<N){
        float val=acc[u][v];
        if(bias) val+=bias[nn];
        if(epi==2) val=0.5f*val*(1.f+erff(val*0.70710678118654752f));
        else if(epi==3) val+=rp[nn];
        op[nn]=val;
      }
    }
  }
}

// ---------------- causal depthwise conv4 + bias + silu over zx cols [384,896) ----------------
__global__ __launch_bounds__(256) void k_conv(const float* __restrict__ zx, const float* __restrict__ cw,
                       const float* __restrict__ cb, float* __restrict__ xbc){
  int e=blockIdx.x*256+threadIdx.x;
  if(e>=2*4608*512) return;
  int ch=e&511; int rl=e>>9;
  int l=rl%4608;
  float acc=cb[ch];
  const float* base=zx+(size_t)rl*902+384+ch;
  float w0=cw[ch*4],w1=cw[ch*4+1],w2=cw[ch*4+2],w3=cw[ch*4+3];
  if(l>=3) acc+=base[-3*902]*w0;
  if(l>=2) acc+=base[-2*902]*w1;
  if(l>=1) acc+=base[-902]*w2;
  acc+=base[0]*w3;
  xbc[e]=siluf_(acc);
}

// ---------------- dt softplus, a = dt*(-exp(A_log)), per-chunk inclusive cumsum ----------------
__global__ __launch_bounds__(128) void k_prep(const float* __restrict__ zx, const float* __restrict__ dt_bias,
    const float* __restrict__ A_log, float* __restrict__ dtb, float* __restrict__ acs, float* __restrict__ csum){
  int bid=blockIdx.x;
  int c=bid%36, h=(bid/36)%6, b=bid/216;
  int l=threadIdx.x;
  int row=b*4608+c*128+l;
  float xv=zx[(size_t)row*902+896+h]+dt_bias[h];
  float dt=softplusf_(xv);
  float a=-__expf(A_log[h])*dt;
  dtb[row*6+h]=dt;
  __shared__ float sb[128];
  sb[l]=a; __syncthreads();
  for(int off=1;off<128;off<<=1){
    float add=(l>=off)? sb[l-off]:0.f;
    __syncthreads();
    sb[l]+=add;
    __syncthreads();
  }
  acs[((size_t)(b*6+h)*36+c)*128+l]=sb[l];
  if(l==127) csum[(b*6+h)*36+c]=sb[127];
}

// ---------------- fused SSD: states + (M = tril(exp)·C·B^T) @ Xd, M kept in LDS ----------------
__global__ __launch_bounds__(256) void k_ssd_a(const float* __restrict__ xbc, const float* __restrict__ dtb,
    const float* __restrict__ acs, const float* __restrict__ csum,
    float* __restrict__ st, float* __restrict__ Y){
  int bid=blockIdx.x;
  int h=bid%6, c=(bid/6)%36, b=bid/216;
  __shared__ float sB[128][68];
  __shared__ float sXd[128][68];
  __shared__ float sC[32][68];
  __shared__ float sM[32][132];
  __shared__ float sAcs[128];
  __shared__ float sE[128];
  int tid=threadIdx.x;
  int base_row=b*4608+c*128;
  const float* acsp=acs+((size_t)(b*6+h)*36+c)*128;
  float tot=csum[(b*6+h)*36+c];
  for(int i=tid;i<8192;i+=256){
    int l=i>>6, n=i&63;
    int row=base_row+l;
    sB[l][n]=xbc[(size_t)row*512+384+n];
    sXd[l][n]=xbc[(size_t)row*512+h*64+n]*dtb[row*6+h];
  }
  if(tid<128){ float a=acsp[tid]; sAcs[tid]=a; sE[tid]=__expf(tot-a); }
  __syncthreads();
  // ---- states: st[p][n] = sum_l Xd[l][p]*E[l]*B[l][n], 4x4 per thread
  {
    int p0=4*(tid>>4), n0=4*(tid&15);
    float acc[4][4]={};
    for(int l=0;l<128;l++){
      float e=sE[l];
      float4 xv=*(const float4*)&sXd[l][p0];
      float4 bv=*(const float4*)&sB[l][n0];
      float a0=xv.x*e,a1=xv.y*e,a2=xv.z*e,a3=xv.w*e;
      acc[0][0]+=a0*bv.x; acc[0][1]+=a0*bv.y; acc[0][2]+=a0*bv.z; acc[0][3]+=a0*bv.w;
      acc[1][0]+=a1*bv.x; acc[1][1]+=a1*bv.y; acc[1][2]+=a1*bv.z; acc[1][3]+=a1*bv.w;
      acc[2][0]+=a2*bv.x; acc[2][1]+=a2*bv.y; acc[2][2]+=a2*bv.z; acc[2][3]+=a2*bv.w;
      acc[3][0]+=a3*bv.x; acc[3][1]+=a3*bv.y; acc[3][2]+=a3*bv.z; acc[3][3]+=a3*bv.w;
    }
    float* op=st+((size_t)((b*36+c)*6+h))*4096;
    #pragma unroll
    for(int u=0;u<4;u++)
      #pragma unroll
      for(int v=0;v<4;v++) op[(p0+u)*64+n0+v]=acc[u][v];
  }
  // ---- per 32-row tile: scores into sM, then Y rows
  for(int jt=0;jt<4;jt++){
    for(int i=tid;i<2048;i+=256){
      int lt=i>>6, n=i&63;
      sC[lt][n]=xbc[(size_t)(base_row+32*jt+lt)*512+448+n];
    }
    __syncthreads();
    {
      int lt0=4*(tid&7), s0=4*(tid>>3);
      int lbase=32*jt+lt0;
      if(s0>lbase+3){
        float4 z={0.f,0.f,0.f,0.f};
        #pragma unroll
        for(int u=0;u<4;u++) *(float4*)&sM[lt0+u][s0]=z;
      } else {
        float d[4][4]={};
        for(int n4=0;n4<64;n4+=4){
          float4 cv[4], bv[4];
          #pragma unroll
          for(int u=0;u<4;u++) cv[u]=*(const float4*)&sC[lt0+u][n4];
          #pragma unroll
          for(int v=0;v<4;v++) bv[v]=*(const float4*)&sB[s0+v][n4];
          #pragma unroll
          for(int u=0;u<4;u++)
            #pragma unroll
            for(int v=0;v<4;v++)
              d[u][v]+=cv[u].x*bv[v].x+cv[u].y*bv[v].y+cv[u].z*bv[v].z+cv[u].w*bv[v].w;
        }
        #pragma unroll
        for(int u=0;u<4;u++){
          int l=lbase+u;
          float4 mv;
          mv.x=(s0+0<=l)? __expf(sAcs[l]-sAcs[s0+0])*d[u][0] : 0.f;
          mv.y=(s0+1<=l)? __expf(sAcs[l]-sAcs[s0+1])*d[u][1] : 0.f;
          mv.z=(s0+2<=l)? __expf(sAcs[l]-sAcs[s0+2])*d[u][2] : 0.f;
          mv.w=(s0+3<=l)? __expf(sAcs[l]-sAcs[s0+3])*d[u][3] : 0.f;
          *(float4*)&sM[lt0+u][s0]=mv;
        }
      }
    }
    __syncthreads();
    {
      int p=tid&63, lg=tid>>6;
      int Send=32*(jt+1);
      float acc[8]={};
      for(int s4=0;s4<Send;s4+=4){
        float xv0=sXd[s4][p],xv1=sXd[s4+1][p],xv2=sXd[s4+2][p],xv3=sXd[s4+3][p];
        #pragma unroll
        for(int j=0;j<8;j++){
          int lt=lg*8+j;
          float4 m=*(const float4*)&sM[lt][s4];
          acc[j]+=m.x*xv0+m.y*xv1+m.z*xv2+m.w*xv3;
        }
      }
      #pragma unroll
      for(int j=0;j<8;j++){
        int lt=lg*8+j;
        int row=base_row+32*jt+lt;
        Y[(size_t)row*384+h*64+p]=acc[j];
      }
    }
    __syncthreads();
  }
}

// ---------------- sequential chunk scan ----------------
__global__ __launch_bounds__(256) void k_scan(const float* __restrict__ st, const float* __restrict__ csum,
                                              float* __restrict__ prevb){
  int bid=blockIdx.x;
  int seg=bid&15, bh=bid>>4;
  int b=bh/6, h=bh%6;
  int e=seg*256+threadIdx.x;
  float carry=0.f;
  for(int c=0;c<36;c++){
    size_t idx=((size_t)((b*36+c)*6+h))*4096+e;
    prevb[idx]=carry;
    carry=carry*__expf(csum[(b*6+h)*36+c])+st[idx];
  }
}

// ---------------- Y += exp(acs[l]) * (C_l · prev[p]) + xp*D[h] ----------------
__global__ __launch_bounds__(256) void k_ssd_b(const float* __restrict__ xbc, const float* __restrict__ prevb,
    const float* __restrict__ acs, const float* __restrict__ Dv, float* __restrict__ Y){
  int bid=blockIdx.x;
  int h=bid%6, c=(bid/6)%36, b=bid/216;
  __shared__ float sC[128][64];
  __shared__ float sP[64][65];
  int tid=threadIdx.x;
  int base_row=b*4608+c*128;
  const float* acsp=acs+((size_t)(b*6+h)*36+c)*128;
  for(int i=tid;i<8192;i+=256){ int l=i>>6,n=i&63; sC[l][n]=xbc[(size_t)(base_row+l)*512+448+n]; }
  const float* pp=prevb+((size_t)((b*36+c)*6+h))*4096;
  for(int i=tid;i<4096;i+=256){ int p_=i>>6,n=i&63; sP[p_][n]=pp[i]; }
  __syncthreads();
  float Dh=Dv[h];
  int p=tid&63, l0=tid>>6;
  #pragma unroll
  for(int j=0;j<32;j++){
    int l=l0+4*j;
    float off=0;
    #pragma unroll 8
    for(int n=0;n<64;n++) off+=sC[l][n]*sP[p][n];
    int row=base_row+l;
    size_t yi=(size_t)row*384+h*64+p;
    float xpv=xbc[(size_t)row*512+h*64+p];
    Y[yi]+=off*__expf(acsp[l])+xpv*Dh;
  }
}

// ---------------- y = Y * silu(z), RMSNorm * norm_w ----------------
__global__ __launch_bounds__(256) void k_rmsgate(const float* __restrict__ Y, const float* __restrict__ zx,
    const float* __restrict__ nw, float* __restrict__ yn){
  int warp=threadIdx.x>>6, lane=threadIdx.x&63;
  int row=blockIdx.x*4+warp;
  float v[6]; float ss=0.f;
  #pragma unroll
  for(int j=0;j<6;j++){
    int cidx=lane+64*j;
    float y=Y[(size_t)row*384+cidx];
    float z=zx[(size_t)row*902+cidx];
    y*=siluf_(z);
    v[j]=y; ss+=y*y;
  }
  #pragma unroll
  for(int off=32;off;off>>=1) ss+=__shfl_xor(ss,off);
  float sc=rsqrtf(ss*(1.f/384.f)+1e-5f);
  #pragma unroll
  for(int j=0;j<6;j++){
    int cidx=lane+64*j;
    yn[(size_t)row*384+cidx]=v[j]*sc*nw[cidx];
  }
}

// ---------------- windowed attention core ----------------
__global__ __launch_bounds__(64) void k_att2(const float* __restrict__ qkv, const float* __restrict__ xn,
    const float* __restrict__ gw, const float* __restrict__ gb, float* __restrict__ obuf){
  int bid=blockIdx.x;
  int widx=bid/6, head=bid-widx*6;
  int b=widx/36, t=widx-b*36;
  int wi=t/6, wj=t-wi*6;
  int n=threadIdx.x;
  __shared__ float sK[64][32], sV[64][32], sS[64][65];
  size_t qbase=(size_t)(widx*64+n)*576;
  float q[32];
  #pragma unroll
  for(int d=0;d<32;d++){
    q[d]=qkv[qbase+head*32+d];
    sK[n][d]=qkv[qbase+192+head*32+d];
    sV[n][d]=qkv[qbase+384+head*32+d];
  }
  int h2=wi*8+(n>>3), w2=wj*8+(n&7);
  int rh=(h2<40)?0:((h2<44)?1:2);
  int rw=(w2<40)?0:((w2<44)?1:2);
  int myid=rh*3+rw;
  __syncthreads();
  const float scale=0.17677669529663687f;
  for(int j=0;j<64;j++){
    float sc=0;
    #pragma unroll
    for(int d=0;d<32;d++) sc+=q[d]*sK[j][d];
    int hj=wi*8+(j>>3), wjj=wj*8+(j&7);
    int rhj=(hj<40)?0:((hj<44)?1:2);
    int rwj=(wjj<40)?0:((wjj<44)?1:2);
    float m=((rhj*3+rwj)!=myid)? -100.f:0.f;
    sS[n][j]=sc*scale+m;
  }
  float mx=-1e30f;
  for(int j=0;j<64;j++) mx=fmaxf(mx,sS[n][j]);
  float den=0;
  for(int j=0;j<64;j++){ float p=__expf(sS[n][j]-mx); sS[n][j]=p; den+=p; }
  float o[32];
  #pragma unroll
  for(int d=0;d<32;d++) o[d]=0.f;
  for(int j=0;j<64;j++){
    float p=sS[n][j];
    #pragma unroll
    for(int d=0;d<32;d++) o[d]+=p*sV[j][d];
  }
  int xrow=map_row(widx*64+n,2);
  const float* xp=xn+(size_t)xrow*192;
  const float* gwp=gw+head*192;
  float g=0;
  for(int cidx=0;cidx<192;cidx+=4){
    float4 xv=*(const float4*)(xp+cidx);
    float4 wv=*(const float4*)(gwp+cidx);
    g+=xv.x*wv.x+xv.y*wv.y+xv.z*wv.z+xv.w*wv.w;
  }
  g=sigmoidf_(g+gb[head]);
  float fac=g/den;
  float* op=obuf+(size_t)(widx*64+n)*192+head*32;
  #pragma unroll
  for(int d=0;d<32;d++) op[d]=o[d]*fac;
}

// ---------------- ECA pooling ----------------
__global__ __launch_bounds__(192) void k_pool1(const float* __restrict__ xf, float* __restrict__ partial){
  int bid=blockIdx.x; int b=bid/18, seg=bid%18;
  int cidx=threadIdx.x;
  const float* p=xf+((size_t)b*2304+seg*128)*192+cidx;
  float s=0;
  for(int l=0;l<128;l++) s+=p[(size_t)l*192];
  partial[bid*192+cidx]=s;
}

__global__ __launch_bounds__(768) void k_ca(const float* __restrict__ partial, const float* __restrict__ ecaw,
                                            float* __restrict__ ca){
  int tid=threadIdx.x;
  int b=tid/192, cidx=tid%192;
  float s=0;
  for(int k=0;k<18;k++) s+=partial[(b*18+k)*192+cidx];
  float pv=s*(1.f/2304.f);
  __shared__ float sP[768];
  sP[tid]=pv; __syncthreads();
  float left =(cidx>0)?   sP[tid-1]:0.f;
  float right=(cidx<191)? sP[tid+1]:0.f;
  ca[tid]=sigmoidf_(ecaw[0]*left+ecaw[1]*pv+ecaw[2]*right);
}

// ---------------- xo = x + xf * ca ----------------
__global__ __launch_bounds__(256) void k_xo(const float* __restrict__ x, const float* __restrict__ xf,
                                            const float* __restrict__ ca, float* __restrict__ xo){
  int e=blockIdx.x*256+threadIdx.x;
  if(e>=4*2304*192) return;
  int cidx=e%192;
  int b=e/(192*2304);
  xo[e]=x[e]+xf[e]*ca[b*192+cidx];
}

extern "C" void kernel_launch(void* const* d_in, const int* in_sizes, int n_in,
                              void* d_out, int out_size, void* d_ws, size_t ws_size,
                              hipStream_t stream){
  const float* x     =(const float*)d_in[0];
  const float* n1w   =(const float*)d_in[3];
  const float* n1b   =(const float*)d_in[4];
  const float* m_in_w=(const float*)d_in[5];
  const float* m_cw  =(const float*)d_in[6];
  const float* m_cb  =(const float*)d_in[7];
  const float* m_dtb =(const float*)d_in[8];
  const float* m_Al  =(const float*)d_in[9];
  const float* m_D   =(const float*)d_in[10];
  const float* m_nw  =(const float*)d_in[11];
  const float* m_ow  =(const float*)d_in[12];
  const float* qkvw  =(const float*)d_in[13];
  const float* qkvb  =(const float*)d_in[14];
  const float* projw =(const float*)d_in[15];
  const float* projb =(const float*)d_in[16];
  const float* gatew =(const float*)d_in[17];
  const float* gateb =(const float*)d_in[18];
  const float* fusw  =(const float*)d_in[19];
  const float* fusb  =(const float*)d_in[20];
  const float* ecaw  =(const float*)d_in[21];
  const float* n2w   =(const float*)d_in[22];
  const float* n2b   =(const float*)d_in[23];
  const float* fc1w  =(const float*)d_in[24];
  const float* fc1b  =(const float*)d_in[25];
  const float* fc2w  =(const float*)d_in[26];
  const float* fc2b  =(const float*)d_in[27];
  float* out=(float*)d_out;
  float* ws=(float*)d_ws;

  // arena (floats); total 25,528,832 floats = 102.1 MB
  float* xn   = ws + 0;          // 1,769,472   LN1 .. att2
  float* zx   = ws + 1769472;    // 8,312,832   in_proj .. rmsgate
  float* xbc  = ws + 10082304;   // 4,718,592   conv .. ssd_b
  float* dtb  = ws + 14800896;   //    55,296   prep .. ssd_a
  float* acs  = ws + 14856192;   //    55,296   prep .. ssd_b
  float* csum = ws + 14911488;   //       512
  float* st   = ws + 14912000;   // 3,538,944   ssd_a .. scan
  float* prevb= ws + 18450944;   // 3,538,944   scan .. ssd_b
  float* Y    = ws + 21989888;   // 3,538,944   ssd_a .. rmsgate
  // aliases (disjoint lifetimes)
  float* yn   = st;              // rmsgate .. out_proj (9216x384)
  float* xcat = prevb;           // out_proj .. fusion (9216x384)
  float* qkv  = zx;              // qkv gemm .. att2 (9216x576)
  float* obuf = xbc;             // att2 .. proj (9216x192)
  float* xf   = st;              // fusion .. xo (9216x192)
  float* xo   = Y;               // xo .. fc2 (9216x192)
  float* hbuf = xn;              // ln2 .. fc1
  float* h1   = zx;              // fc1 .. fc2 (9216x768)
  float* partial = dtb;          // pool
  float* ca   = acs;             // ca .. xo

  // 1. LN1
  k_ln<<<2304,256,0,stream>>>(x,n1w,n1b,xn);
  // 2. in_proj (gather: mamba interleave)
  k_gemm2<<<dim3(15,72),256,0,stream>>>(xn,m_in_w,nullptr,nullptr,zx, 902,192, 192,902,0, 1,0,0);
  // 3. depthwise conv + silu
  k_conv<<<18432,256,0,stream>>>(zx,m_cw,m_cb,xbc);
  // 4. dt/cumsum prep
  k_prep<<<432,128,0,stream>>>(zx,m_dtb,m_Al,dtb,acs,csum);
  // 5. fused SSD part A: states + diagonal Y
  k_ssd_a<<<432,256,0,stream>>>(xbc,dtb,acs,csum,st,Y);
  // 6. chunk scan
  k_scan<<<192,256,0,stream>>>(st,csum,prevb);
  // 7. off-diagonal + D residual
  k_ssd_b<<<432,256,0,stream>>>(xbc,prevb,acs,m_D,Y);
  // 8. gated RMS norm
  k_rmsgate<<<2304,256,0,stream>>>(Y,zx,m_nw,yn);
  // 9. mamba out_proj -> xcat[:, 0:192] (scatter: de-interleave)
  k_gemm2<<<dim3(3,72),256,0,stream>>>(yn,m_ow,nullptr,nullptr,xcat, 192,384, 384,384,0, 0,1,0);
  // 10. qkv (gather: shifted windows)
  k_gemm2<<<dim3(9,72),256,0,stream>>>(xn,qkvw,qkvb,nullptr,qkv, 576,192, 192,576,0, 2,0,0);
  // 11. attention core + gate
  k_att2<<<864,64,0,stream>>>(qkv,xn,gatew,gateb,obuf);
  // 12. attn proj -> xcat[:, 192:384] (scatter: reverse windows)
  k_gemm2<<<dim3(3,72),256,0,stream>>>(obuf,projw,projb,nullptr,xcat, 192,192, 192,384,192, 0,2,0);
  // 13. fusion
  k_gemm2<<<dim3(3,72),256,0,stream>>>(xcat,fusw,fusb,nullptr,xf, 192,384, 384,192,0, 0,0,0);
  // 14. ECA
  k_pool1<<<72,192,0,stream>>>(xf,partial);
  k_ca<<<1,768,0,stream>>>(partial,ecaw,ca);
  // 15. xo = x + xf*ca
  k_xo<<<6912,256,0,stream>>>(x,xf,ca,xo);
  // 16. LN2
  k_ln<<<2304,256,0,stream>>>(xo,n2w,n2b,hbuf);
  // 17. fc1 + gelu
  k_gemm2<<<dim3(12,72),256,0,stream>>>(hbuf,fc1w,fc1b,nullptr,h1, 768,192, 192,768,0, 0,0,2);
  // 18. fc2 + residual -> out
  k_gemm2<<<dim3(3,72),256,0,stream>>>(h1,fc2w,fc2b,xo,out, 192,768, 768,192,0, 0,0,3);
}

// Round 3
// 330.673 us; speedup vs baseline: 1.7468x; 1.6792x over previous
//
#include <hip/hip_runtime.h>
#include <math.h>

#define DEV __device__ __forceinline__

typedef __attribute__((ext_vector_type(8))) short short8;
typedef __attribute__((ext_vector_type(4))) float f32x4;

DEV float sigmoidf_(float x){ return 1.f/(1.f+__expf(-x)); }
DEV float siluf_(float x){ return x/(1.f+__expf(-x)); }
DEV float softplusf_(float x){ return (x>20.f)? x : log1pf(__expf(x)); }

DEV short bf16rne(float f){
  unsigned u=__float_as_uint(f);
  unsigned r=(u + 0x7FFFu + ((u>>16)&1u))>>16;
  return (short)r;
}
DEV float b2f(unsigned short u){ return __uint_as_float(((unsigned)u)<<16); }
DEV float4 ld4b(const unsigned short* p){
  float4 r; r.x=b2f(p[0]); r.y=b2f(p[1]); r.z=b2f(p[2]); r.w=b2f(p[3]); return r;
}

// row index remap: mode 0 identity; mode 1 mamba interleave/deinterleave;
// mode 2 shifted-window gather/scatter (roll -4,-4 then 8x8 windows)
DEV int map_row(int r, int mode){
  if(mode==1){
    int b=r/4608; int gl=r-b*4608;
    return ((gl&1)*2+b)*2304 + (gl>>1);
  }
  if(mode==2){
    int widx=r>>6, n=r&63;
    int b=widx/36, t=widx-b*36;
    int wi=t/6, wj=t-wi*6;
    int h2=wi*8+(n>>3), w2=wj*8+(n&7);
    int ho=h2+4; if(ho>=48) ho-=48;
    int wo=w2+4; if(wo>=48) wo-=48;
    return b*2304 + ho*48 + wo;
  }
  return r;
}

// ---------------- LayerNorm over C=192, 4 rows (waves) per block ----------------
__global__ __launch_bounds__(256) void k_ln(const float* __restrict__ in, const float* __restrict__ w,
                                            const float* __restrict__ b, float* __restrict__ out){
  int warp=threadIdx.x>>6, lane=threadIdx.x&63;
  int row=blockIdx.x*4+warp;
  const float* ip=in+(size_t)row*192;
  float v0=ip[lane], v1=ip[lane+64], v2=ip[lane+128];
  float s=v0+v1+v2, sq=v0*v0+v1*v1+v2*v2;
  #pragma unroll
  for(int off=32;off;off>>=1){ s+=__shfl_xor(s,off); sq+=__shfl_xor(sq,off); }
  float mean=s*(1.f/192.f), var=sq*(1.f/192.f)-mean*mean;
  float inv=rsqrtf(var+1e-5f);
  float* op=out+(size_t)row*192;
  op[lane]    =(v0-mean)*inv*w[lane]    +b[lane];
  op[lane+64] =(v1-mean)*inv*w[lane+64] +b[lane+64];
  op[lane+128]=(v2-mean)*inv*w[lane+128]+b[lane+128];
}

// ---------------- bf16 MFMA GEMM: Out[map_s(m)][col_off+n] = A[map_g(m)]·W[n]^T ----------------
// BM x 64 tile, BK=32, 256 thr (4 waves, 2x2), fp32 accumulate.
// epi: 0 none/bias, 2 bias+gelu, 3 bias+res
template<int BM>
__global__ __launch_bounds__(256) void k_gemm_mfma(const float* __restrict__ A, const float* __restrict__ W,
    const float* __restrict__ bias, const float* __restrict__ res, float* __restrict__ O,
    int N, int K, int lda, int ldo, int col_off, int gmode, int smode, int epi){
  constexpr int MREP = BM/32;              // m-frags per wave
  __shared__ short sA[BM][40];
  __shared__ short sB[64][40];
  int tid=threadIdx.x;
  int lane=tid&63, wid=tid>>6;
  int wr=wid>>1, wc=wid&1;
  int bm=blockIdx.y*BM, bn=blockIdx.x*64;
  // A staging: each thread loads BM/8 floats of one row-chunk
  int ar, ak;
  if(BM==128){ ar=tid>>1; ak=(tid&1)*16; } else { ar=tid>>2; ak=(tid&3)*8; }
  int arow=map_row(bm+ar,gmode);
  const float* Ap=A+(size_t)arow*lda+ak;
  // B staging: 8 floats each
  int br=tid>>2, bk=(tid&3)*8;
  bool bok=(bn+br)<N;
  const float* Wp=W+(size_t)(bok?(bn+br):0)*K+bk;
  f32x4 acc[MREP][2];
  #pragma unroll
  for(int mi=0;mi<MREP;mi++)
    #pragma unroll
    for(int ni=0;ni<2;ni++) acc[mi][ni]=(f32x4){0.f,0.f,0.f,0.f};
  int m16=lane&15, kq=lane>>4;

  for(int k0=0;k0<K;k0+=32){
    float av[16];
    if(BM==128){
      float4 t0=*(const float4*)(Ap+0), t1=*(const float4*)(Ap+4);
      float4 t2=*(const float4*)(Ap+8), t3=*(const float4*)(Ap+12);
      av[0]=t0.x;av[1]=t0.y;av[2]=t0.z;av[3]=t0.w; av[4]=t1.x;av[5]=t1.y;av[6]=t1.z;av[7]=t1.w;
      av[8]=t2.x;av[9]=t2.y;av[10]=t2.z;av[11]=t2.w; av[12]=t3.x;av[13]=t3.y;av[14]=t3.z;av[15]=t3.w;
    } else {
      float4 t0=*(const float4*)(Ap+0), t1=*(const float4*)(Ap+4);
      av[0]=t0.x;av[1]=t0.y;av[2]=t0.z;av[3]=t0.w; av[4]=t1.x;av[5]=t1.y;av[6]=t1.z;av[7]=t1.w;
    }
    float bv[8]={};
    if(bok){
      float4 t0=*(const float4*)(Wp+0), t1=*(const float4*)(Wp+4);
      bv[0]=t0.x;bv[1]=t0.y;bv[2]=t0.z;bv[3]=t0.w; bv[4]=t1.x;bv[5]=t1.y;bv[6]=t1.z;bv[7]=t1.w;
    }
    __syncthreads();   // previous iteration's reads complete
    if(BM==128){
      short8 w0,w1;
      #pragma unroll
      for(int j=0;j<8;j++) w0[j]=bf16rne(av[j]);
      #pragma unroll
      for(int j=0;j<8;j++) w1[j]=bf16rne(av[8+j]);
      *(short8*)&sA[ar][ak]  =w0;
      *(short8*)&sA[ar][ak+8]=w1;
    } else {
      short8 w0;
      #pragma unroll
      for(int j=0;j<8;j++) w0[j]=bf16rne(av[j]);
      *(short8*)&sA[ar][ak]=w0;
    }
    {
      short8 w0;
      #pragma unroll
      for(int j=0;j<8;j++) w0[j]=bf16rne(bv[j]);
      *(short8*)&sB[br][bk]=w0;
    }
    __syncthreads();
    short8 af[MREP], bfr[2];
    #pragma unroll
    for(int mi=0;mi<MREP;mi++) af[mi]=*(const short8*)&sA[wr*(BM/2)+mi*16+m16][kq*8];
    #pragma unroll
    for(int ni=0;ni<2;ni++) bfr[ni]=*(const short8*)&sB[wc*32+ni*16+m16][kq*8];
    #pragma unroll
    for(int mi=0;mi<MREP;mi++)
      #pragma unroll
      for(int ni=0;ni<2;ni++)
        acc[mi][ni]=__builtin_amdgcn_mfma_f32_16x16x32_bf16(af[mi],bfr[ni],acc[mi][ni],0,0,0);
    Ap+=32; Wp+=32;
  }
  // epilogue: D row=4*kq+reg, col=m16
  #pragma unroll
  for(int mi=0;mi<MREP;mi++){
    #pragma unroll
    for(int r=0;r<4;r++){
      int m=bm + wr*(BM/2) + mi*16 + 4*kq + r;
      int orow=map_row(m,smode);
      float* op=O+(size_t)orow*ldo+col_off;
      const float* rp=res? res+(size_t)orow*ldo : nullptr;
      #pragma unroll
      for(int ni=0;ni<2;ni++){
        int nn=bn + wc*32 + ni*16 + m16;
        if(nn<N){
          float val=acc[mi][ni][r];
          if(bias) val+=bias[nn];
          if(epi==2) val=0.5f*val*(1.f+erff(val*0.70710678118654752f));
          else if(epi==3) val+=rp[nn];
          op[nn]=val;
        }
      }
    }
  }
}

// ---------------- causal depthwise conv4 + bias + silu over zx cols [384,896) ----------------
__global__ __launch_bounds__(256) void k_conv(const float* __restrict__ zx, const float* __restrict__ cw,
                       const float* __restrict__ cb, float* __restrict__ xbc){
  int e=blockIdx.x*256+threadIdx.x;
  if(e>=2*4608*512) return;
  int ch=e&511; int rl=e>>9;
  int l=rl%4608;
  float acc=cb[ch];
  const float* base=zx+(size_t)rl*902+384+ch;
  float w0=cw[ch*4],w1=cw[ch*4+1],w2=cw[ch*4+2],w3=cw[ch*4+3];
  if(l>=3) acc+=base[-3*902]*w0;
  if(l>=2) acc+=base[-2*902]*w1;
  if(l>=1) acc+=base[-902]*w2;
  acc+=base[0]*w3;
  xbc[e]=siluf_(acc);
}

// ---------------- dt softplus, a = dt*(-exp(A_log)), per-chunk inclusive cumsum ----------------
__global__ __launch_bounds__(128) void k_prep(const float* __restrict__ zx, const float* __restrict__ dt_bias,
    const float* __restrict__ A_log, float* __restrict__ dtb, float* __restrict__ acs, float* __restrict__ csum){
  int bid=blockIdx.x;
  int c=bid%36, h=(bid/36)%6, b=bid/216;
  int l=threadIdx.x;
  int row=b*4608+c*128+l;
  float xv=zx[(size_t)row*902+896+h]+dt_bias[h];
  float dt=softplusf_(xv);
  float a=-__expf(A_log[h])*dt;
  dtb[row*6+h]=dt;
  __shared__ float sb[128];
  sb[l]=a; __syncthreads();
  for(int off=1;off<128;off<<=1){
    float add=(l>=off)? sb[l-off]:0.f;
    __syncthreads();
    sb[l]+=add;
    __syncthreads();
  }
  acs[((size_t)(b*6+h)*36+c)*128+l]=sb[l];
  if(l==127) csum[(b*6+h)*36+c]=sb[127];
}

// ---------------- fused SSD: states + (M = tril(exp)·C·B^T) @ Xd, M kept in LDS ----------------
// B/Xd/C tiles in bf16 (57 KB LDS total -> 2 blocks/CU)
__global__ __launch_bounds__(256) void k_ssd_a(const float* __restrict__ xbc, const float* __restrict__ dtb,
    const float* __restrict__ acs, const float* __restrict__ csum,
    float* __restrict__ st, float* __restrict__ Y){
  int bid=blockIdx.x;
  int h=bid%6, c=(bid/6)%36, b=bid/216;
  __shared__ unsigned short sB[128][68];
  __shared__ unsigned short sXd[128][68];
  __shared__ unsigned short sC[32][68];
  __shared__ float sM[32][132];
  __shared__ float sAcs[128];
  __shared__ float sE[128];
  int tid=threadIdx.x;
  int base_row=b*4608+c*128;
  const float* acsp=acs+((size_t)(b*6+h)*36+c)*128;
  float tot=csum[(b*6+h)*36+c];
  for(int i=tid;i<8192;i+=256){
    int l=i>>6, n=i&63;
    int row=base_row+l;
    sB[l][n]=(unsigned short)bf16rne(xbc[(size_t)row*512+384+n]);
    sXd[l][n]=(unsigned short)bf16rne(xbc[(size_t)row*512+h*64+n]*dtb[row*6+h]);
  }
  if(tid<128){ float a=acsp[tid]; sAcs[tid]=a; sE[tid]=__expf(tot-a); }
  __syncthreads();
  // ---- states: st[p][n] = sum_l Xd[l][p]*E[l]*B[l][n], 4x4 per thread
  {
    int p0=4*(tid>>4), n0=4*(tid&15);
    float acc[4][4]={};
    for(int l=0;l<128;l++){
      float e=sE[l];
      float4 xv=ld4b(&sXd[l][p0]);
      float4 bv=ld4b(&sB[l][n0]);
      float a0=xv.x*e,a1=xv.y*e,a2=xv.z*e,a3=xv.w*e;
      acc[0][0]+=a0*bv.x; acc[0][1]+=a0*bv.y; acc[0][2]+=a0*bv.z; acc[0][3]+=a0*bv.w;
      acc[1][0]+=a1*bv.x; acc[1][1]+=a1*bv.y; acc[1][2]+=a1*bv.z; acc[1][3]+=a1*bv.w;
      acc[2][0]+=a2*bv.x; acc[2][1]+=a2*bv.y; acc[2][2]+=a2*bv.z; acc[2][3]+=a2*bv.w;
      acc[3][0]+=a3*bv.x; acc[3][1]+=a3*bv.y; acc[3][2]+=a3*bv.z; acc[3][3]+=a3*bv.w;
    }
    float* op=st+((size_t)((b*36+c)*6+h))*4096;
    #pragma unroll
    for(int u=0;u<4;u++)
      #pragma unroll
      for(int v=0;v<4;v++) op[(p0+u)*64+n0+v]=acc[u][v];
  }
  // ---- per 32-row tile: scores into sM, then Y rows
  for(int jt=0;jt<4;jt++){
    for(int i=tid;i<2048;i+=256){
      int lt=i>>6, n=i&63;
      sC[lt][n]=(unsigned short)bf16rne(xbc[(size_t)(base_row+32*jt+lt)*512+448+n]);
    }
    __syncthreads();
    {
      int lt0=4*(tid&7), s0=4*(tid>>3);
      int lbase=32*jt+lt0;
      if(s0>lbase+3){
        float4 z={0.f,0.f,0.f,0.f};
        #pragma unroll
        for(int u=0;u<4;u++) *(float4*)&sM[lt0+u][s0]=z;
      } else {
        float d[4][4]={};
        for(int n4=0;n4<64;n4+=4){
          float4 cv[4], bv[4];
          #pragma unroll
          for(int u=0;u<4;u++) cv[u]=ld4b(&sC[lt0+u][n4]);
          #pragma unroll
          for(int v=0;v<4;v++) bv[v]=ld4b(&sB[s0+v][n4]);
          #pragma unroll
          for(int u=0;u<4;u++)
            #pragma unroll
            for(int v=0;v<4;v++)
              d[u][v]+=cv[u].x*bv[v].x+cv[u].y*bv[v].y+cv[u].z*bv[v].z+cv[u].w*bv[v].w;
        }
        #pragma unroll
        for(int u=0;u<4;u++){
          int l=lbase+u;
          float4 mv;
          mv.x=(s0+0<=l)? __expf(sAcs[l]-sAcs[s0+0])*d[u][0] : 0.f;
          mv.y=(s0+1<=l)? __expf(sAcs[l]-sAcs[s0+1])*d[u][1] : 0.f;
          mv.z=(s0+2<=l)? __expf(sAcs[l]-sAcs[s0+2])*d[u][2] : 0.f;
          mv.w=(s0+3<=l)? __expf(sAcs[l]-sAcs[s0+3])*d[u][3] : 0.f;
          *(float4*)&sM[lt0+u][s0]=mv;
        }
      }
    }
    __syncthreads();
    {
      int p=tid&63, lg=tid>>6;
      int Send=32*(jt+1);
      float acc[8]={};
      for(int s4=0;s4<Send;s4+=4){
        float xv0=b2f(sXd[s4][p]),xv1=b2f(sXd[s4+1][p]),xv2=b2f(sXd[s4+2][p]),xv3=b2f(sXd[s4+3][p]);
        #pragma unroll
        for(int j=0;j<8;j++){
          int lt=lg*8+j;
          float4 m=*(const float4*)&sM[lt][s4];
          acc[j]+=m.x*xv0+m.y*xv1+m.z*xv2+m.w*xv3;
        }
      }
      #pragma unroll
      for(int j=0;j<8;j++){
        int lt=lg*8+j;
        int row=base_row+32*jt+lt;
        Y[(size_t)row*384+h*64+p]=acc[j];
      }
    }
    __syncthreads();
  }
}

// ---------------- sequential chunk scan ----------------
__global__ __launch_bounds__(256) void k_scan(const float* __restrict__ st, const float* __restrict__ csum,
                                              float* __restrict__ prevb){
  int bid=blockIdx.x;
  int seg=bid&15, bh=bid>>4;
  int b=bh/6, h=bh%6;
  int e=seg*256+threadIdx.x;
  float carry=0.f;
  for(int c=0;c<36;c++){
    size_t idx=((size_t)((b*36+c)*6+h))*4096+e;
    prevb[idx]=carry;
    carry=carry*__expf(csum[(b*6+h)*36+c])+st[idx];
  }
}

// ---------------- Y += exp(acs[l]) * (C_l · prev[p]) + xp*D[h] ----------------
__global__ __launch_bounds__(256) void k_ssd_b(const float* __restrict__ xbc, const float* __restrict__ prevb,
    const float* __restrict__ acs, const float* __restrict__ Dv, float* __restrict__ Y){
  int bid=blockIdx.x;
  int h=bid%6, c=(bid/6)%36, b=bid/216;
  __shared__ float sC[128][64];
  __shared__ float sP[64][65];
  int tid=threadIdx.x;
  int base_row=b*4608+c*128;
  const float* acsp=acs+((size_t)(b*6+h)*36+c)*128;
  for(int i=tid;i<8192;i+=256){ int l=i>>6,n=i&63; sC[l][n]=xbc[(size_t)(base_row+l)*512+448+n]; }
  const float* pp=prevb+((size_t)((b*36+c)*6+h))*4096;
  for(int i=tid;i<4096;i+=256){ int p_=i>>6,n=i&63; sP[p_][n]=pp[i]; }
  __syncthreads();
  float Dh=Dv[h];
  int p=tid&63, l0=tid>>6;
  #pragma unroll
  for(int j=0;j<32;j++){
    int l=l0+4*j;
    float off=0;
    #pragma unroll 8
    for(int n=0;n<64;n++) off+=sC[l][n]*sP[p][n];
    int row=base_row+l;
    size_t yi=(size_t)row*384+h*64+p;
    float xpv=xbc[(size_t)row*512+h*64+p];
    Y[yi]+=off*__expf(acsp[l])+xpv*Dh;
  }
}

// ---------------- y = Y * silu(z), RMSNorm * norm_w ----------------
__global__ __launch_bounds__(256) void k_rmsgate(const float* __restrict__ Y, const float* __restrict__ zx,
    const float* __restrict__ nw, float* __restrict__ yn){
  int warp=threadIdx.x>>6, lane=threadIdx.x&63;
  int row=blockIdx.x*4+warp;
  float v[6]; float ss=0.f;
  #pragma unroll
  for(int j=0;j<6;j++){
    int cidx=lane+64*j;
    float y=Y[(size_t)row*384+cidx];
    float z=zx[(size_t)row*902+cidx];
    y*=siluf_(z);
    v[j]=y; ss+=y*y;
  }
  #pragma unroll
  for(int off=32;off;off>>=1) ss+=__shfl_xor(ss,off);
  float sc=rsqrtf(ss*(1.f/384.f)+1e-5f);
  #pragma unroll
  for(int j=0;j<6;j++){
    int cidx=lane+64*j;
    yn[(size_t)row*384+cidx]=v[j]*sc*nw[cidx];
  }
}

// ---------------- windowed attention core ----------------
__global__ __launch_bounds__(64) void k_att2(const float* __restrict__ qkv, const float* __restrict__ xn,
    const float* __restrict__ gw, const float* __restrict__ gb, float* __restrict__ obuf){
  int bid=blockIdx.x;
  int widx=bid/6, head=bid-widx*6;
  int b=widx/36, t=widx-b*36;
  int wi=t/6, wj=t-wi*6;
  int n=threadIdx.x;
  __shared__ float sK[64][32], sV[64][32], sS[64][65];
  size_t qbase=(size_t)(widx*64+n)*576;
  float q[32];
  #pragma unroll
  for(int d=0;d<32;d++){
    q[d]=qkv[qbase+head*32+d];
    sK[n][d]=qkv[qbase+192+head*32+d];
    sV[n][d]=qkv[qbase+384+head*32+d];
  }
  int h2=wi*8+(n>>3), w2=wj*8+(n&7);
  int rh=(h2<40)?0:((h2<44)?1:2);
  int rw=(w2<40)?0:((w2<44)?1:2);
  int myid=rh*3+rw;
  __syncthreads();
  const float scale=0.17677669529663687f;
  for(int j=0;j<64;j++){
    float sc=0;
    #pragma unroll
    for(int d=0;d<32;d++) sc+=q[d]*sK[j][d];
    int hj=wi*8+(j>>3), wjj=wj*8+(j&7);
    int rhj=(hj<40)?0:((hj<44)?1:2);
    int rwj=(wjj<40)?0:((wjj<44)?1:2);
    float m=((rhj*3+rwj)!=myid)? -100.f:0.f;
    sS[n][j]=sc*scale+m;
  }
  float mx=-1e30f;
  for(int j=0;j<64;j++) mx=fmaxf(mx,sS[n][j]);
  float den=0;
  for(int j=0;j<64;j++){ float p=__expf(sS[n][j]-mx); sS[n][j]=p; den+=p; }
  float o[32];
  #pragma unroll
  for(int d=0;d<32;d++) o[d]=0.f;
  for(int j=0;j<64;j++){
    float p=sS[n][j];
    #pragma unroll
    for(int d=0;d<32;d++) o[d]+=p*sV[j][d];
  }
  int xrow=map_row(widx*64+n,2);
  const float* xp=xn+(size_t)xrow*192;
  const float* gwp=gw+head*192;
  float g=0;
  for(int cidx=0;cidx<192;cidx+=4){
    float4 xv=*(const float4*)(xp+cidx);
    float4 wv=*(const float4*)(gwp+cidx);
    g+=xv.x*wv.x+xv.y*wv.y+xv.z*wv.z+xv.w*wv.w;
  }
  g=sigmoidf_(g+gb[head]);
  float fac=g/den;
  float* op=obuf+(size_t)(widx*64+n)*192+head*32;
  #pragma unroll
  for(int d=0;d<32;d++) op[d]=o[d]*fac;
}

// ---------------- ECA pooling ----------------
__global__ __launch_bounds__(192) void k_pool1(const float* __restrict__ xf, float* __restrict__ partial){
  int bid=blockIdx.x; int b=bid/18, seg=bid%18;
  int cidx=threadIdx.x;
  const float* p=xf+((size_t)b*2304+seg*128)*192+cidx;
  float s=0;
  for(int l=0;l<128;l++) s+=p[(size_t)l*192];
  partial[bid*192+cidx]=s;
}

__global__ __launch_bounds__(768) void k_ca(const float* __restrict__ partial, const float* __restrict__ ecaw,
                                            float* __restrict__ ca){
  int tid=threadIdx.x;
  int b=tid/192, cidx=tid%192;
  float s=0;
  for(int k=0;k<18;k++) s+=partial[(b*18+k)*192+cidx];
  float pv=s*(1.f/2304.f);
  __shared__ float sP[768];
  sP[tid]=pv; __syncthreads();
  float left =(cidx>0)?   sP[tid-1]:0.f;
  float right=(cidx<191)? sP[tid+1]:0.f;
  ca[tid]=sigmoidf_(ecaw[0]*left+ecaw[1]*pv+ecaw[2]*right);
}

// ---------------- xo = x + xf * ca ----------------
__global__ __launch_bounds__(256) void k_xo(const float* __restrict__ x, const float* __restrict__ xf,
                                            const float* __restrict__ ca, float* __restrict__ xo){
  int e=blockIdx.x*256+threadIdx.x;
  if(e>=4*2304*192) return;
  int cidx=e%192;
  int b=e/(192*2304);
  xo[e]=x[e]+xf[e]*ca[b*192+cidx];
}

extern "C" void kernel_launch(void* const* d_in, const int* in_sizes, int n_in,
                              void* d_out, int out_size, void* d_ws, size_t ws_size,
                              hipStream_t stream){
  const float* x     =(const float*)d_in[0];
  const float* n1w   =(const float*)d_in[3];
  const float* n1b   =(const float*)d_in[4];
  const float* m_in_w=(const float*)d_in[5];
  const float* m_cw  =(const float*)d_in[6];
  const float* m_cb  =(const float*)d_in[7];
  const float* m_dtb =(const float*)d_in[8];
  const float* m_Al  =(const float*)d_in[9];
  const float* m_D   =(const float*)d_in[10];
  const float* m_nw  =(const float*)d_in[11];
  const float* m_ow  =(const float*)d_in[12];
  const float* qkvw  =(const float*)d_in[13];
  const float* qkvb  =(const float*)d_in[14];
  const float* projw =(const float*)d_in[15];
  const float* projb =(const float*)d_in[16];
  const float* gatew =(const float*)d_in[17];
  const float* gateb =(const float*)d_in[18];
  const float* fusw  =(const float*)d_in[19];
  const float* fusb  =(const float*)d_in[20];
  const float* ecaw  =(const float*)d_in[21];
  const float* n2w   =(const float*)d_in[22];
  const float* n2b   =(const float*)d_in[23];
  const float* fc1w  =(const float*)d_in[24];
  const float* fc1b  =(const float*)d_in[25];
  const float* fc2w  =(const float*)d_in[26];
  const float* fc2b  =(const float*)d_in[27];
  float* out=(float*)d_out;
  float* ws=(float*)d_ws;

  // arena (floats); total 25,528,832 floats = 102.1 MB
  float* xn   = ws + 0;          // 1,769,472   LN1 .. att2
  float* zx   = ws + 1769472;    // 8,312,832   in_proj .. rmsgate
  float* xbc  = ws + 10082304;   // 4,718,592   conv .. ssd_b
  float* dtb  = ws + 14800896;   //    55,296   prep .. ssd_a
  float* acs  = ws + 14856192;   //    55,296   prep .. ssd_b
  float* csum = ws + 14911488;   //       512
  float* st   = ws + 14912000;   // 3,538,944   ssd_a .. scan
  float* prevb= ws + 18450944;   // 3,538,944   scan .. ssd_b
  float* Y    = ws + 21989888;   // 3,538,944   ssd_a .. rmsgate
  // aliases (disjoint lifetimes)
  float* yn   = st;              // rmsgate .. out_proj (9216x384)
  float* xcat = prevb;           // out_proj .. fusion (9216x384)
  float* qkv  = zx;              // qkv gemm .. att2 (9216x576)
  float* obuf = xbc;             // att2 .. proj (9216x192)
  float* xf   = st;              // fusion .. xo (9216x192)
  float* xo   = Y;               // xo .. fc2 (9216x192)
  float* hbuf = xn;              // ln2 .. fc1
  float* h1   = zx;              // fc1 .. fc2 (9216x768)
  float* partial = dtb;          // pool
  float* ca   = acs;             // ca .. xo

  // 1. LN1
  k_ln<<<2304,256,0,stream>>>(x,n1w,n1b,xn);
  // 2. in_proj (gather: mamba interleave)
  k_gemm_mfma<128><<<dim3(15,72),256,0,stream>>>(xn,m_in_w,nullptr,nullptr,zx, 902,192, 192,902,0, 1,0,0);
  // 3. depthwise conv + silu
  k_conv<<<18432,256,0,stream>>>(zx,m_cw,m_cb,xbc);
  // 4. dt/cumsum prep
  k_prep<<<432,128,0,stream>>>(zx,m_dtb,m_Al,dtb,acs,csum);
  // 5. fused SSD part A: states + diagonal Y
  k_ssd_a<<<432,256,0,stream>>>(xbc,dtb,acs,csum,st,Y);
  // 6. chunk scan
  k_scan<<<192,256,0,stream>>>(st,csum,prevb);
  // 7. off-diagonal + D residual
  k_ssd_b<<<432,256,0,stream>>>(xbc,prevb,acs,m_D,Y);
  // 8. gated RMS norm
  k_rmsgate<<<2304,256,0,stream>>>(Y,zx,m_nw,yn);
  // 9. mamba out_proj -> xcat[:, 0:192] (scatter: de-interleave)
  k_gemm_mfma<64><<<dim3(3,144),256,0,stream>>>(yn,m_ow,nullptr,nullptr,xcat, 192,384, 384,384,0, 0,1,0);
  // 10. qkv (gather: shifted windows)
  k_gemm_mfma<128><<<dim3(9,72),256,0,stream>>>(xn,qkvw,qkvb,nullptr,qkv, 576,192, 192,576,0, 2,0,0);
  // 11. attention core + gate
  k_att2<<<864,64,0,stream>>>(qkv,xn,gatew,gateb,obuf);
  // 12. attn proj -> xcat[:, 192:384] (scatter: reverse windows)
  k_gemm_mfma<64><<<dim3(3,144),256,0,stream>>>(obuf,projw,projb,nullptr,xcat, 192,192, 192,384,192, 0,2,0);
  // 13. fusion
  k_gemm_mfma<64><<<dim3(3,144),256,0,stream>>>(xcat,fusw,fusb,nullptr,xf, 192,384, 384,192,0, 0,0,0);
  // 14. ECA
  k_pool1<<<72,192,0,stream>>>(xf,partial);
  k_ca<<<1,768,0,stream>>>(partial,ecaw,ca);
  // 15. xo = x + xf*ca
  k_xo<<<6912,256,0,stream>>>(x,xf,ca,xo);
  // 16. LN2
  k_ln<<<2304,256,0,stream>>>(xo,n2w,n2b,hbuf);
  // 17. fc1 + gelu
  k_gemm_mfma<128><<<dim3(12,72),256,0,stream>>>(hbuf,fc1w,fc1b,nullptr,h1, 768,192, 192,768,0, 0,0,2);
  // 18. fc2 + residual -> out
  k_gemm_mfma<64><<<dim3(3,144),256,0,stream>>>(h1,fc2w,fc2b,xo,out, 192,768, 768,192,0, 0,0,3);
}

// Round 4
// 266.563 us; speedup vs baseline: 2.1669x; 1.2405x over previous
//
#include <hip/hip_runtime.h>
#include <math.h>

#define DEV __device__ __forceinline__

typedef __attribute__((ext_vector_type(8))) short short8;
typedef __attribute__((ext_vector_type(4))) float f32x4;

DEV float sigmoidf_(float x){ return 1.f/(1.f+__expf(-x)); }
DEV float siluf_(float x){ return x/(1.f+__expf(-x)); }
DEV float softplusf_(float x){ return (x>20.f)? x : log1pf(__expf(x)); }

DEV short bf16rne(float f){
  unsigned u=__float_as_uint(f);
  unsigned r=(u + 0x7FFFu + ((u>>16)&1u))>>16;
  return (short)r;
}
DEV unsigned short bf16u(float f){ return (unsigned short)bf16rne(f); }

// row index remap: mode 0 identity; mode 1 mamba interleave/deinterleave;
// mode 2 shifted-window gather/scatter (roll -4,-4 then 8x8 windows)
DEV int map_row(int r, int mode){
  if(mode==1){
    int b=r/4608; int gl=r-b*4608;
    return ((gl&1)*2+b)*2304 + (gl>>1);
  }
  if(mode==2){
    int widx=r>>6, n=r&63;
    int b=widx/36, t=widx-b*36;
    int wi=t/6, wj=t-wi*6;
    int h2=wi*8+(n>>3), w2=wj*8+(n&7);
    int ho=h2+4; if(ho>=48) ho-=48;
    int wo=w2+4; if(wo>=48) wo-=48;
    return b*2304 + ho*48 + wo;
  }
  return r;
}

// ---------------- LayerNorm over C=192, 4 rows (waves) per block ----------------
__global__ __launch_bounds__(256) void k_ln(const float* __restrict__ in, const float* __restrict__ w,
                                            const float* __restrict__ b, float* __restrict__ out){
  int warp=threadIdx.x>>6, lane=threadIdx.x&63;
  int row=blockIdx.x*4+warp;
  const float* ip=in+(size_t)row*192;
  float v0=ip[lane], v1=ip[lane+64], v2=ip[lane+128];
  float s=v0+v1+v2, sq=v0*v0+v1*v1+v2*v2;
  #pragma unroll
  for(int off=32;off;off>>=1){ s+=__shfl_xor(s,off); sq+=__shfl_xor(sq,off); }
  float mean=s*(1.f/192.f), var=sq*(1.f/192.f)-mean*mean;
  float inv=rsqrtf(var+1e-5f);
  float* op=out+(size_t)row*192;
  op[lane]    =(v0-mean)*inv*w[lane]    +b[lane];
  op[lane+64] =(v1-mean)*inv*w[lane+64] +b[lane+64];
  op[lane+128]=(v2-mean)*inv*w[lane+128]+b[lane+128];
}

// ---------------- bf16 MFMA GEMM: Out[map_s(m)][col_off+n] = A[map_g(m)]·W[n]^T ----------------
template<int BM>
__global__ __launch_bounds__(256) void k_gemm_mfma(const float* __restrict__ A, const float* __restrict__ W,
    const float* __restrict__ bias, const float* __restrict__ res, float* __restrict__ O,
    int N, int K, int lda, int ldo, int col_off, int gmode, int smode, int epi){
  constexpr int MREP = BM/32;
  __shared__ short sA[BM][40];
  __shared__ short sB[64][40];
  int tid=threadIdx.x;
  int lane=tid&63, wid=tid>>6;
  int wr=wid>>1, wc=wid&1;
  int bm=blockIdx.y*BM, bn=blockIdx.x*64;
  int ar, ak;
  if(BM==128){ ar=tid>>1; ak=(tid&1)*16; } else { ar=tid>>2; ak=(tid&3)*8; }
  int arow=map_row(bm+ar,gmode);
  const float* Ap=A+(size_t)arow*lda+ak;
  int br=tid>>2, bk=(tid&3)*8;
  bool bok=(bn+br)<N;
  const float* Wp=W+(size_t)(bok?(bn+br):0)*K+bk;
  f32x4 acc[MREP][2];
  #pragma unroll
  for(int mi=0;mi<MREP;mi++)
    #pragma unroll
    for(int ni=0;ni<2;ni++) acc[mi][ni]=(f32x4){0.f,0.f,0.f,0.f};
  int m16=lane&15, kq=lane>>4;

  for(int k0=0;k0<K;k0+=32){
    float av[16];
    if(BM==128){
      float4 t0=*(const float4*)(Ap+0), t1=*(const float4*)(Ap+4);
      float4 t2=*(const float4*)(Ap+8), t3=*(const float4*)(Ap+12);
      av[0]=t0.x;av[1]=t0.y;av[2]=t0.z;av[3]=t0.w; av[4]=t1.x;av[5]=t1.y;av[6]=t1.z;av[7]=t1.w;
      av[8]=t2.x;av[9]=t2.y;av[10]=t2.z;av[11]=t2.w; av[12]=t3.x;av[13]=t3.y;av[14]=t3.z;av[15]=t3.w;
    } else {
      float4 t0=*(const float4*)(Ap+0), t1=*(const float4*)(Ap+4);
      av[0]=t0.x;av[1]=t0.y;av[2]=t0.z;av[3]=t0.w; av[4]=t1.x;av[5]=t1.y;av[6]=t1.z;av[7]=t1.w;
    }
    float bv[8]={};
    if(bok){
      float4 t0=*(const float4*)(Wp+0), t1=*(const float4*)(Wp+4);
      bv[0]=t0.x;bv[1]=t0.y;bv[2]=t0.z;bv[3]=t0.w; bv[4]=t1.x;bv[5]=t1.y;bv[6]=t1.z;bv[7]=t1.w;
    }
    __syncthreads();
    if(BM==128){
      short8 w0,w1;
      #pragma unroll
      for(int j=0;j<8;j++) w0[j]=bf16rne(av[j]);
      #pragma unroll
      for(int j=0;j<8;j++) w1[j]=bf16rne(av[8+j]);
      *(short8*)&sA[ar][ak]  =w0;
      *(short8*)&sA[ar][ak+8]=w1;
    } else {
      short8 w0;
      #pragma unroll
      for(int j=0;j<8;j++) w0[j]=bf16rne(av[j]);
      *(short8*)&sA[ar][ak]=w0;
    }
    {
      short8 w0;
      #pragma unroll
      for(int j=0;j<8;j++) w0[j]=bf16rne(bv[j]);
      *(short8*)&sB[br][bk]=w0;
    }
    __syncthreads();
    short8 af[MREP], bfr[2];
    #pragma unroll
    for(int mi=0;mi<MREP;mi++) af[mi]=*(const short8*)&sA[wr*(BM/2)+mi*16+m16][kq*8];
    #pragma unroll
    for(int ni=0;ni<2;ni++) bfr[ni]=*(const short8*)&sB[wc*32+ni*16+m16][kq*8];
    #pragma unroll
    for(int mi=0;mi<MREP;mi++)
      #pragma unroll
      for(int ni=0;ni<2;ni++)
        acc[mi][ni]=__builtin_amdgcn_mfma_f32_16x16x32_bf16(af[mi],bfr[ni],acc[mi][ni],0,0,0);
    Ap+=32; Wp+=32;
  }
  #pragma unroll
  for(int mi=0;mi<MREP;mi++){
    #pragma unroll
    for(int r=0;r<4;r++){
      int m=bm + wr*(BM/2) + mi*16 + 4*kq + r;
      int orow=map_row(m,smode);
      float* op=O+(size_t)orow*ldo+col_off;
      const float* rp=res? res+(size_t)orow*ldo : nullptr;
      #pragma unroll
      for(int ni=0;ni<2;ni++){
        int nn=bn + wc*32 + ni*16 + m16;
        if(nn<N){
          float val=acc[mi][ni][r];
          if(bias) val+=bias[nn];
          if(epi==2) val=0.5f*val*(1.f+erff(val*0.70710678118654752f));
          else if(epi==3) val+=rp[nn];
          op[nn]=val;
        }
      }
    }
  }
}

// ---------------- causal depthwise conv4 + bias + silu over zx cols [384,896) ----------------
__global__ __launch_bounds__(256) void k_conv(const float* __restrict__ zx, const float* __restrict__ cw,
                       const float* __restrict__ cb, float* __restrict__ xbc){
  int e=blockIdx.x*256+threadIdx.x;
  if(e>=2*4608*512) return;
  int ch=e&511; int rl=e>>9;
  int l=rl%4608;
  float acc=cb[ch];
  const float* base=zx+(size_t)rl*902+384+ch;
  float w0=cw[ch*4],w1=cw[ch*4+1],w2=cw[ch*4+2],w3=cw[ch*4+3];
  if(l>=3) acc+=base[-3*902]*w0;
  if(l>=2) acc+=base[-2*902]*w1;
  if(l>=1) acc+=base[-902]*w2;
  acc+=base[0]*w3;
  xbc[e]=siluf_(acc);
}

// ---------------- dt softplus, a = dt*(-exp(A_log)), per-chunk inclusive cumsum ----------------
__global__ __launch_bounds__(128) void k_prep(const float* __restrict__ zx, const float* __restrict__ dt_bias,
    const float* __restrict__ A_log, float* __restrict__ dtb, float* __restrict__ acs, float* __restrict__ csum){
  int bid=blockIdx.x;
  int c=bid%36, h=(bid/36)%6, b=bid/216;
  int l=threadIdx.x;
  int row=b*4608+c*128+l;
  float xv=zx[(size_t)row*902+896+h]+dt_bias[h];
  float dt=softplusf_(xv);
  float a=-__expf(A_log[h])*dt;
  dtb[row*6+h]=dt;
  __shared__ float sb[128];
  sb[l]=a; __syncthreads();
  for(int off=1;off<128;off<<=1){
    float add=(l>=off)? sb[l-off]:0.f;
    __syncthreads();
    sb[l]+=add;
    __syncthreads();
  }
  acs[((size_t)(b*6+h)*36+c)*128+l]=sb[l];
  if(l==127) csum[(b*6+h)*36+c]=sb[127];
}

// ---------------- fused SSD part A (MFMA): states + diagonal Y, M kept in wave-private LDS ----------------
__global__ __launch_bounds__(256) void k_ssd_a(const float* __restrict__ xbc, const float* __restrict__ dtb,
    const float* __restrict__ acs, const float* __restrict__ csum,
    float* __restrict__ st, float* __restrict__ Y){
  int bid=blockIdx.x;
  int h=bid%6, c=(bid/6)%36, b=bid/216;
  __shared__ unsigned short sB[128][68];    // B rows (l, n-contig)      : scores B-op
  __shared__ unsigned short sC[128][68];    // C rows (l, n-contig)      : scores A-op
  __shared__ unsigned short sXdT[64][132];  // Xd^T rows (p, l-contig)   : states A-op, Y1 B-op
  __shared__ unsigned short sBTE[64][132];  // (B*E)^T rows (n, l-contig): states B-op
  __shared__ unsigned short sM[128][36];    // M slab rows (l, s-contig, per-slab local cols)
  __shared__ float sAcs[128];
  __shared__ float sE[128];
  int tid=threadIdx.x;
  int lane=tid&63, wid=tid>>6;
  int m16=lane&15, kq=lane>>4;
  int base_row=b*4608+c*128;
  const float* acsp=acs+((size_t)(b*6+h)*36+c)*128;
  float tot=csum[(b*6+h)*36+c];
  if(tid<128){ float a=acsp[tid]; sAcs[tid]=a; sE[tid]=__expf(tot-a); }
  __syncthreads();
  for(int i=tid;i<8192;i+=256){
    int l=i>>6, n=i&63;
    int row=base_row+l;
    float Bv=xbc[(size_t)row*512+384+n];
    float Cv=xbc[(size_t)row*512+448+n];
    float Xv=xbc[(size_t)row*512+h*64+n]*dtb[row*6+h];
    sB[l][n]=bf16u(Bv);
    sC[l][n]=bf16u(Cv);
    sXdT[n][l]=bf16u(Xv);
    sBTE[n][l]=bf16u(Bv*sE[l]);
  }
  __syncthreads();
  // ---- Phase A: states st[p][n] = sum_l XdT[p][l]*BTE[n][l]  (M=64,N=64,K=128)
  {
    int wr=wid>>1, wc=wid&1;
    f32x4 accS[2][2];
    #pragma unroll
    for(int mi=0;mi<2;mi++)
      #pragma unroll
      for(int ni=0;ni<2;ni++) accS[mi][ni]=(f32x4){0.f,0.f,0.f,0.f};
    #pragma unroll
    for(int ks=0;ks<4;ks++){
      short8 a0=*(const short8*)&sXdT[wr*32+m16][ks*32+kq*8];
      short8 a1=*(const short8*)&sXdT[wr*32+16+m16][ks*32+kq*8];
      short8 b0=*(const short8*)&sBTE[wc*32+m16][ks*32+kq*8];
      short8 b1=*(const short8*)&sBTE[wc*32+16+m16][ks*32+kq*8];
      accS[0][0]=__builtin_amdgcn_mfma_f32_16x16x32_bf16(a0,b0,accS[0][0],0,0,0);
      accS[0][1]=__builtin_amdgcn_mfma_f32_16x16x32_bf16(a0,b1,accS[0][1],0,0,0);
      accS[1][0]=__builtin_amdgcn_mfma_f32_16x16x32_bf16(a1,b0,accS[1][0],0,0,0);
      accS[1][1]=__builtin_amdgcn_mfma_f32_16x16x32_bf16(a1,b1,accS[1][1],0,0,0);
    }
    float* op=st+((size_t)((b*36+c)*6+h))*4096;
    #pragma unroll
    for(int mi=0;mi<2;mi++)
      #pragma unroll
      for(int ni=0;ni<2;ni++)
        #pragma unroll
        for(int r=0;r<4;r++){
          int p=wr*32+mi*16+4*kq+r, n=wc*32+ni*16+m16;
          op[p*64+n]=accS[mi][ni][r];
        }
  }
  // ---- Phase B: per l-tile {wid, 7-wid}: scores slab -> exp/mask -> M -> Y accumulate.
  // Wave-private M rows; no barriers needed.
  #pragma unroll
  for(int ti=0;ti<2;ti++){
    int t = ti? (7-wid) : wid;
    f32x4 accY[4];
    #pragma unroll
    for(int pi=0;pi<4;pi++) accY[pi]=(f32x4){0.f,0.f,0.f,0.f};
    int nslab=(t>>1)+1;
    for(int jt=0;jt<nslab;jt++){
      f32x4 accD[2];
      accD[0]=(f32x4){0.f,0.f,0.f,0.f}; accD[1]=(f32x4){0.f,0.f,0.f,0.f};
      #pragma unroll
      for(int ks=0;ks<2;ks++){
        short8 a =*(const short8*)&sC[t*16+m16][ks*32+kq*8];
        short8 b0=*(const short8*)&sB[jt*32+m16][ks*32+kq*8];
        short8 b1=*(const short8*)&sB[jt*32+16+m16][ks*32+kq*8];
        accD[0]=__builtin_amdgcn_mfma_f32_16x16x32_bf16(a,b0,accD[0],0,0,0);
        accD[1]=__builtin_amdgcn_mfma_f32_16x16x32_bf16(a,b1,accD[1],0,0,0);
      }
      int lrow=t*16+4*kq;
      #pragma unroll
      for(int sti=0;sti<2;sti++)
        #pragma unroll
        for(int r=0;r<4;r++){
          int l=lrow+r, s=jt*32+sti*16+m16;
          float v=(s<=l)? __expf(sAcs[l]-sAcs[s])*accD[sti][r] : 0.f;
          sM[l][sti*16+m16]=bf16u(v);
        }
      short8 am=*(const short8*)&sM[t*16+m16][kq*8];
      #pragma unroll
      for(int pi=0;pi<4;pi++){
        short8 bx=*(const short8*)&sXdT[pi*16+m16][jt*32+kq*8];
        accY[pi]=__builtin_amdgcn_mfma_f32_16x16x32_bf16(am,bx,accY[pi],0,0,0);
      }
    }
    #pragma unroll
    for(int pi=0;pi<4;pi++)
      #pragma unroll
      for(int r=0;r<4;r++){
        int l=t*16+4*kq+r, p=pi*16+m16;
        Y[(size_t)(base_row+l)*384+h*64+p]=accY[pi][r];
      }
  }
}

// ---------------- sequential chunk scan ----------------
__global__ __launch_bounds__(256) void k_scan(const float* __restrict__ st, const float* __restrict__ csum,
                                              float* __restrict__ prevb){
  int bid=blockIdx.x;
  int seg=bid&15, bh=bid>>4;
  int b=bh/6, h=bh%6;
  int e=seg*256+threadIdx.x;
  float carry=0.f;
  for(int c=0;c<36;c++){
    size_t idx=((size_t)((b*36+c)*6+h))*4096+e;
    prevb[idx]=carry;
    carry=carry*__expf(csum[(b*6+h)*36+c])+st[idx];
  }
}

// ---------------- SSD part B (MFMA): Y += exp(acs[l])*(C_l · prev[p]) + xp*D[h] ----------------
__global__ __launch_bounds__(256) void k_ssd_b(const float* __restrict__ xbc, const float* __restrict__ prevb,
    const float* __restrict__ acs, const float* __restrict__ Dv, float* __restrict__ Y){
  int bid=blockIdx.x;
  int h=bid%6, c=(bid/6)%36, b=bid/216;
  __shared__ unsigned short sC[128][68];
  __shared__ unsigned short sP[64][68];
  __shared__ float sAcs[128];
  int tid=threadIdx.x;
  int lane=tid&63, wid=tid>>6;
  int m16=lane&15, kq=lane>>4;
  int base_row=b*4608+c*128;
  const float* acsp=acs+((size_t)(b*6+h)*36+c)*128;
  if(tid<128) sAcs[tid]=acsp[tid];
  for(int i=tid;i<8192;i+=256){ int l=i>>6,n=i&63; sC[l][n]=bf16u(xbc[(size_t)(base_row+l)*512+448+n]); }
  const float* pp=prevb+((size_t)((b*36+c)*6+h))*4096;
  for(int i=tid;i<4096;i+=256){ int p_=i>>6,n=i&63; sP[p_][n]=bf16u(pp[i]); }
  __syncthreads();
  float Dh=Dv[h];
  int lt0=2*wid;
  f32x4 acc[2][4];
  #pragma unroll
  for(int li=0;li<2;li++)
    #pragma unroll
    for(int pi=0;pi<4;pi++) acc[li][pi]=(f32x4){0.f,0.f,0.f,0.f};
  #pragma unroll
  for(int ks=0;ks<2;ks++){
    short8 a0=*(const short8*)&sC[lt0*16+m16][ks*32+kq*8];
    short8 a1=*(const short8*)&sC[(lt0+1)*16+m16][ks*32+kq*8];
    #pragma unroll
    for(int pi=0;pi<4;pi++){
      short8 bp=*(const short8*)&sP[pi*16+m16][ks*32+kq*8];
      acc[0][pi]=__builtin_amdgcn_mfma_f32_16x16x32_bf16(a0,bp,acc[0][pi],0,0,0);
      acc[1][pi]=__builtin_amdgcn_mfma_f32_16x16x32_bf16(a1,bp,acc[1][pi],0,0,0);
    }
  }
  #pragma unroll
  for(int li=0;li<2;li++){
    #pragma unroll
    for(int r=0;r<4;r++){
      int l=(lt0+li)*16+4*kq+r;
      int row=base_row+l;
      float e=__expf(sAcs[l]);
      #pragma unroll
      for(int pi=0;pi<4;pi++){
        int p=pi*16+m16;
        size_t yi=(size_t)row*384+h*64+p;
        float xpv=xbc[(size_t)row*512+h*64+p];
        Y[yi]+=acc[li][pi][r]*e+xpv*Dh;
      }
    }
  }
}

// ---------------- y = Y * silu(z), RMSNorm * norm_w ----------------
__global__ __launch_bounds__(256) void k_rmsgate(const float* __restrict__ Y, const float* __restrict__ zx,
    const float* __restrict__ nw, float* __restrict__ yn){
  int warp=threadIdx.x>>6, lane=threadIdx.x&63;
  int row=blockIdx.x*4+warp;
  float v[6]; float ss=0.f;
  #pragma unroll
  for(int j=0;j<6;j++){
    int cidx=lane+64*j;
    float y=Y[(size_t)row*384+cidx];
    float z=zx[(size_t)row*902+cidx];
    y*=siluf_(z);
    v[j]=y; ss+=y*y;
  }
  #pragma unroll
  for(int off=32;off;off>>=1) ss+=__shfl_xor(ss,off);
  float sc=rsqrtf(ss*(1.f/384.f)+1e-5f);
  #pragma unroll
  for(int j=0;j<6;j++){
    int cidx=lane+64*j;
    yn[(size_t)row*384+cidx]=v[j]*sc*nw[cidx];
  }
}

// ---------------- windowed attention core ----------------
__global__ __launch_bounds__(64) void k_att2(const float* __restrict__ qkv, const float* __restrict__ xn,
    const float* __restrict__ gw, const float* __restrict__ gb, float* __restrict__ obuf){
  int bid=blockIdx.x;
  int widx=bid/6, head=bid-widx*6;
  int b=widx/36, t=widx-b*36;
  int wi=t/6, wj=t-wi*6;
  int n=threadIdx.x;
  __shared__ float sK[64][32], sV[64][32], sS[64][65];
  size_t qbase=(size_t)(widx*64+n)*576;
  float q[32];
  #pragma unroll
  for(int d=0;d<32;d++){
    q[d]=qkv[qbase+head*32+d];
    sK[n][d]=qkv[qbase+192+head*32+d];
    sV[n][d]=qkv[qbase+384+head*32+d];
  }
  int h2=wi*8+(n>>3), w2=wj*8+(n&7);
  int rh=(h2<40)?0:((h2<44)?1:2);
  int rw=(w2<40)?0:((w2<44)?1:2);
  int myid=rh*3+rw;
  __syncthreads();
  const float scale=0.17677669529663687f;
  for(int j=0;j<64;j++){
    float sc=0;
    #pragma unroll
    for(int d=0;d<32;d++) sc+=q[d]*sK[j][d];
    int hj=wi*8+(j>>3), wjj=wj*8+(j&7);
    int rhj=(hj<40)?0:((hj<44)?1:2);
    int rwj=(wjj<40)?0:((wjj<44)?1:2);
    float m=((rhj*3+rwj)!=myid)? -100.f:0.f;
    sS[n][j]=sc*scale+m;
  }
  float mx=-1e30f;
  for(int j=0;j<64;j++) mx=fmaxf(mx,sS[n][j]);
  float den=0;
  for(int j=0;j<64;j++){ float p=__expf(sS[n][j]-mx); sS[n][j]=p; den+=p; }
  float o[32];
  #pragma unroll
  for(int d=0;d<32;d++) o[d]=0.f;
  for(int j=0;j<64;j++){
    float p=sS[n][j];
    #pragma unroll
    for(int d=0;d<32;d++) o[d]+=p*sV[j][d];
  }
  int xrow=map_row(widx*64+n,2);
  const float* xp=xn+(size_t)xrow*192;
  const float* gwp=gw+head*192;
  float g=0;
  for(int cidx=0;cidx<192;cidx+=4){
    float4 xv=*(const float4*)(xp+cidx);
    float4 wv=*(const float4*)(gwp+cidx);
    g+=xv.x*wv.x+xv.y*wv.y+xv.z*wv.z+xv.w*wv.w;
  }
  g=sigmoidf_(g+gb[head]);
  float fac=g/den;
  float* op=obuf+(size_t)(widx*64+n)*192+head*32;
  #pragma unroll
  for(int d=0;d<32;d++) op[d]=o[d]*fac;
}

// ---------------- ECA pooling ----------------
__global__ __launch_bounds__(192) void k_pool1(const float* __restrict__ xf, float* __restrict__ partial){
  int bid=blockIdx.x; int b=bid/18, seg=bid%18;
  int cidx=threadIdx.x;
  const float* p=xf+((size_t)b*2304+seg*128)*192+cidx;
  float s=0;
  for(int l=0;l<128;l++) s+=p[(size_t)l*192];
  partial[bid*192+cidx]=s;
}

__global__ __launch_bounds__(768) void k_ca(const float* __restrict__ partial, const float* __restrict__ ecaw,
                                            float* __restrict__ ca){
  int tid=threadIdx.x;
  int b=tid/192, cidx=tid%192;
  float s=0;
  for(int k=0;k<18;k++) s+=partial[(b*18+k)*192+cidx];
  float pv=s*(1.f/2304.f);
  __shared__ float sP[768];
  sP[tid]=pv; __syncthreads();
  float left =(cidx>0)?   sP[tid-1]:0.f;
  float right=(cidx<191)? sP[tid+1]:0.f;
  ca[tid]=sigmoidf_(ecaw[0]*left+ecaw[1]*pv+ecaw[2]*right);
}

// ---------------- xo = x + xf * ca ----------------
__global__ __launch_bounds__(256) void k_xo(const float* __restrict__ x, const float* __restrict__ xf,
                                            const float* __restrict__ ca, float* __restrict__ xo){
  int e=blockIdx.x*256+threadIdx.x;
  if(e>=4*2304*192) return;
  int cidx=e%192;
  int b=e/(192*2304);
  xo[e]=x[e]+xf[e]*ca[b*192+cidx];
}

extern "C" void kernel_launch(void* const* d_in, const int* in_sizes, int n_in,
                              void* d_out, int out_size, void* d_ws, size_t ws_size,
                              hipStream_t stream){
  const float* x     =(const float*)d_in[0];
  const float* n1w   =(const float*)d_in[3];
  const float* n1b   =(const float*)d_in[4];
  const float* m_in_w=(const float*)d_in[5];
  const float* m_cw  =(const float*)d_in[6];
  const float* m_cb  =(const float*)d_in[7];
  const float* m_dtb =(const float*)d_in[8];
  const float* m_Al  =(const float*)d_in[9];
  const float* m_D   =(const float*)d_in[10];
  const float* m_nw  =(const float*)d_in[11];
  const float* m_ow  =(const float*)d_in[12];
  const float* qkvw  =(const float*)d_in[13];
  const float* qkvb  =(const float*)d_in[14];
  const float* projw =(const float*)d_in[15];
  const float* projb =(const float*)d_in[16];
  const float* gatew =(const float*)d_in[17];
  const float* gateb =(const float*)d_in[18];
  const float* fusw  =(const float*)d_in[19];
  const float* fusb  =(const float*)d_in[20];
  const float* ecaw  =(const float*)d_in[21];
  const float* n2w   =(const float*)d_in[22];
  const float* n2b   =(const float*)d_in[23];
  const float* fc1w  =(const float*)d_in[24];
  const float* fc1b  =(const float*)d_in[25];
  const float* fc2w  =(const float*)d_in[26];
  const float* fc2b  =(const float*)d_in[27];
  float* out=(float*)d_out;
  float* ws=(float*)d_ws;

  float* xn   = ws + 0;          // 1,769,472   LN1 .. att2
  float* zx   = ws + 1769472;    // 8,312,832   in_proj .. rmsgate
  float* xbc  = ws + 10082304;   // 4,718,592   conv .. ssd_b
  float* dtb  = ws + 14800896;   //    55,296   prep .. ssd_a
  float* acs  = ws + 14856192;   //    55,296   prep .. ssd_b
  float* csum = ws + 14911488;   //       512
  float* st   = ws + 14912000;   // 3,538,944   ssd_a .. scan
  float* prevb= ws + 18450944;   // 3,538,944   scan .. ssd_b
  float* Y    = ws + 21989888;   // 3,538,944   ssd_a .. rmsgate
  // aliases (disjoint lifetimes)
  float* yn   = st;              // rmsgate .. out_proj (9216x384)
  float* xcat = prevb;           // out_proj .. fusion (9216x384)
  float* qkv  = zx;              // qkv gemm .. att2 (9216x576)
  float* obuf = xbc;             // att2 .. proj (9216x192)
  float* xf   = st;              // fusion .. xo (9216x192)
  float* xo   = Y;               // xo .. fc2 (9216x192)
  float* hbuf = xn;              // ln2 .. fc1
  float* h1   = zx;              // fc1 .. fc2 (9216x768)
  float* partial = dtb;          // pool
  float* ca   = acs;             // ca .. xo

  k_ln<<<2304,256,0,stream>>>(x,n1w,n1b,xn);
  k_gemm_mfma<128><<<dim3(15,72),256,0,stream>>>(xn,m_in_w,nullptr,nullptr,zx, 902,192, 192,902,0, 1,0,0);
  k_conv<<<18432,256,0,stream>>>(zx,m_cw,m_cb,xbc);
  k_prep<<<432,128,0,stream>>>(zx,m_dtb,m_Al,dtb,acs,csum);
  k_ssd_a<<<432,256,0,stream>>>(xbc,dtb,acs,csum,st,Y);
  k_scan<<<192,256,0,stream>>>(st,csum,prevb);
  k_ssd_b<<<432,256,0,stream>>>(xbc,prevb,acs,m_D,Y);
  k_rmsgate<<<2304,256,0,stream>>>(Y,zx,m_nw,yn);
  k_gemm_mfma<64><<<dim3(3,144),256,0,stream>>>(yn,m_ow,nullptr,nullptr,xcat, 192,384, 384,384,0, 0,1,0);
  k_gemm_mfma<128><<<dim3(9,72),256,0,stream>>>(xn,qkvw,qkvb,nullptr,qkv, 576,192, 192,576,0, 2,0,0);
  k_att2<<<864,64,0,stream>>>(qkv,xn,gatew,gateb,obuf);
  k_gemm_mfma<64><<<dim3(3,144),256,0,stream>>>(obuf,projw,projb,nullptr,xcat, 192,192, 192,384,192, 0,2,0);
  k_gemm_mfma<64><<<dim3(3,144),256,0,stream>>>(xcat,fusw,fusb,nullptr,xf, 192,384, 384,192,0, 0,0,0);
  k_pool1<<<72,192,0,stream>>>(xf,partial);
  k_ca<<<1,768,0,stream>>>(partial,ecaw,ca);
  k_xo<<<6912,256,0,stream>>>(x,xf,ca,xo);
  k_ln<<<2304,256,0,stream>>>(xo,n2w,n2b,hbuf);
  k_gemm_mfma<128><<<dim3(12,72),256,0,stream>>>(hbuf,fc1w,fc1b,nullptr,h1, 768,192, 192,768,0, 0,0,2);
  k_gemm_mfma<64><<<dim3(3,144),256,0,stream>>>(h1,fc2w,fc2b,xo,out, 192,768, 768,192,0, 0,0,3);
}